// Round 1
// baseline (337.935 us; speedup 1.0000x reference)
//
#include <hip/hip_runtime.h>
#include <stdint.h>

#define B_ 2
#define S_ 4096
#define D_ 512
#define H_ 8
#define DH_ 64
#define M_ (B_*S_)   // 8192

typedef unsigned short u16;
typedef __bf16 bf16x8 __attribute__((ext_vector_type(8)));
typedef float f32x4 __attribute__((ext_vector_type(4)));

__device__ __forceinline__ u16 f2bf(float f) {
  unsigned u = __float_as_uint(f);
  u += 0x7fffu + ((u >> 16) & 1u);
  return (u16)(u >> 16);
}

// global -> LDS direct copy, 16B per lane; LDS dest = wave-uniform base + lane*16
__device__ __forceinline__ void gl_lds16(const void* g, void* l) {
  __builtin_amdgcn_global_load_lds(
      (__attribute__((address_space(1))) void*)(void*)g,
      (__attribute__((address_space(3))) void*)l, 16, 0, 0);
}

// ---------------- x fp32 -> bf16 ----------------
__global__ void k_cvt(const float* __restrict__ x, u16* __restrict__ xb, int n4) {
  int i = blockIdx.x * 256 + threadIdx.x;
  if (i < n4) {
    float4 v = ((const float4*)x)[i];
    uint2 p;
    p.x = (unsigned)f2bf(v.x) | ((unsigned)f2bf(v.y) << 16);
    p.y = (unsigned)f2bf(v.z) | ((unsigned)f2bf(v.w) << 16);
    ((uint2*)xb)[i] = p;
  }
}

// ---------------- W [K,N] fp32 -> Wt [N,K] bf16 (tile transpose) ----------------
__global__ void k_twt(const float* __restrict__ w0, const float* __restrict__ w1,
                      const float* __restrict__ w2, const float* __restrict__ w3,
                      u16* __restrict__ t0, u16* __restrict__ t1,
                      u16* __restrict__ t2, u16* __restrict__ t3) {
  __shared__ float t[32][33];
  int z = blockIdx.z;
  const float* w = z == 0 ? w0 : z == 1 ? w1 : z == 2 ? w2 : w3;
  u16* wt       = z == 0 ? t0 : z == 1 ? t1 : z == 2 ? t2 : t3;
  int n0 = blockIdx.x * 32, k0 = blockIdx.y * 32;
  int tx = threadIdx.x, ty = threadIdx.y;  // 32 x 8
  #pragma unroll
  for (int j = 0; j < 4; j++) t[ty + 8*j][tx] = w[(k0 + ty + 8*j) * D_ + n0 + tx];
  __syncthreads();
  #pragma unroll
  for (int j = 0; j < 4; j++) wt[(n0 + ty + 8*j) * D_ + k0 + tx] = f2bf(t[tx][ty + 8*j]);
}

// ---------------- GEMM: C[m,n] = relu(A[m,:] . Bt[n,:] + bias[n]) * scale ----------------
// A: [M_,512] bf16 row-major (k contig). Bt: [512,512] bf16 (n-major, k contig).
// mode 0: bf16 out [B,H,S,DH]; mode 1: bf16 out [B,H,DH,S]; mode 2: f32 out [M_,D_].
// LDS tiles stored with 16B-chunk XOR swizzle: chunk' = chunk ^ (row & 7),
// realized by pre-swizzling the GLOBAL source address (LDS dest stays linear).
__global__ __launch_bounds__(512, 2)
void k_gemm(const u16* __restrict__ A, const u16* __restrict__ Bt,
            const float* __restrict__ bias, void* __restrict__ out,
            float scale, int mode) {
  __shared__ __align__(16) u16 Al[128*64];
  __shared__ __align__(16) u16 Bl[128*64];
  int tid = threadIdx.x;
  int lane = tid & 63, w = tid >> 6;     // 8 waves: 2 (m) x 4 (n)
  int wr = w >> 2, wc = w & 3;
  int m0 = blockIdx.y * 128, n0 = blockIdx.x * 128;
  int swzc = ((lane & 7) ^ (lane >> 3)) * 8;  // swizzled source chunk, in u16 elems
  int lr8 = lane >> 3;

  f32x4 acc[4][2] = {};

  for (int k0 = 0; k0 < D_; k0 += 64) {
    #pragma unroll
    for (int j = 0; j < 2; j++) {
      int r0 = (w*2 + j) * 8;            // 8 rows per wave-call, r0 % 8 == 0
      gl_lds16(A  + (m0 + r0 + lr8) * D_ + k0 + swzc, &Al[r0 * 64]);
      gl_lds16(Bt + (n0 + r0 + lr8) * D_ + k0 + swzc, &Bl[r0 * 64]);
    }
    __syncthreads();
    #pragma unroll
    for (int h = 0; h < 2; h++) {
      bf16x8 a[4], bq[2];
      #pragma unroll
      for (int i = 0; i < 4; i++) {
        int row = wr*64 + i*16 + (lane & 15);
        int c = (h*4 + (lane >> 4)) ^ (row & 7);
        a[i] = *(const bf16x8*)&Al[row*64 + c*8];
      }
      #pragma unroll
      for (int jn = 0; jn < 2; jn++) {
        int row = wc*32 + jn*16 + (lane & 15);
        int c = (h*4 + (lane >> 4)) ^ (row & 7);
        bq[jn] = *(const bf16x8*)&Bl[row*64 + c*8];
      }
      #pragma unroll
      for (int i = 0; i < 4; i++)
        #pragma unroll
        for (int jn = 0; jn < 2; jn++)
          acc[i][jn] = __builtin_amdgcn_mfma_f32_16x16x32_bf16(a[i], bq[jn], acc[i][jn], 0, 0, 0);
    }
    __syncthreads();
  }

  #pragma unroll
  for (int i = 0; i < 4; i++)
    #pragma unroll
    for (int jn = 0; jn < 2; jn++)
      #pragma unroll
      for (int ii = 0; ii < 4; ii++) {
        int row = m0 + wr*64 + i*16 + (lane >> 4)*4 + ii;
        int col = n0 + wc*32 + jn*16 + (lane & 15);
        float v = acc[i][jn][ii] + bias[col];
        v = fmaxf(v, 0.0f) * scale;
        if (mode == 2) {
          ((float*)out)[row * D_ + col] = v;
        } else {
          int bb = row >> 12, ss = row & (S_ - 1);
          int hh = col >> 6,  dd = col & 63;
          u16 bv = f2bf(v);
          if (mode == 0)
            ((u16*)out)[((bb*H_ + hh)*S_ + ss)*DH_ + dd] = bv;   // [B,H,S,DH]
          else
            ((u16*)out)[((bb*H_ + hh)*DH_ + dd)*S_ + ss] = bv;   // [B,H,DH,S]
        }
      }
}

// ---------------- flash attention ----------------
// Q: [B,H,S,64] bf16 (pre-scaled by 1/8), K: [B,H,S,64] bf16, Vt: [B,H,64,S] bf16.
// O: [B,S,512] bf16 (heads merged). Block = 8 waves x 16 q-rows, KV tile 64.
__global__ __launch_bounds__(512, 2)
void k_attn(const u16* __restrict__ Q, const u16* __restrict__ K,
            const u16* __restrict__ Vt, u16* __restrict__ O) {
  __shared__ __align__(16) u16 Kl[64*64];
  __shared__ __align__(16) u16 Vl[64*64];      // V^T tile: [dh][key]
  __shared__ __align__(16) u16 Pl[8][16*72];   // per-wave P, row stride 72 (144B)
  int tid = threadIdx.x;
  int lane = tid & 63, w = tid >> 6;
  int qt = blockIdx.x, h = blockIdx.y, b = blockIdx.z;
  const u16* Qh = Q  + ((b*H_ + h) * S_) * DH_;
  const u16* Kh = K  + ((b*H_ + h) * S_) * DH_;
  const u16* Vh = Vt + ((b*H_ + h) * DH_) * S_;

  int q0 = qt*128 + w*16;
  bf16x8 aq[2];
  #pragma unroll
  for (int hh = 0; hh < 2; hh++)
    aq[hh] = *(const bf16x8*)&Qh[(q0 + (lane & 15))*DH_ + hh*32 + (lane >> 4)*8];

  f32x4 oacc[4] = {};
  float mrow[4], lrow[4];
  #pragma unroll
  for (int i = 0; i < 4; i++) { mrow[i] = -1e30f; lrow[i] = 0.0f; }

  int swzc = ((lane & 7) ^ (lane >> 3)) * 8;
  int lr8 = lane >> 3;

  for (int kv0 = 0; kv0 < S_; kv0 += 64) {
    // stage K tile [64 keys][64 dh] and V^T tile [64 dh][64 keys], swizzled source
    gl_lds16(Kh + (kv0 + w*8 + lr8)*DH_ + swzc, &Kl[w*8*64]);
    gl_lds16(Vh + (w*8 + lr8)*S_ + kv0 + swzc, &Vl[w*8*64]);
    __syncthreads();

    // S = Q . K^T  (C-layout: qrow = (lane>>4)*4+i, key = kt*16 + (lane&15))
    f32x4 s[4];
    #pragma unroll
    for (int kt = 0; kt < 4; kt++) {
      int row = kt*16 + (lane & 15);
      f32x4 z = {0.f, 0.f, 0.f, 0.f};
      #pragma unroll
      for (int hh = 0; hh < 2; hh++) {
        int c = (hh*4 + (lane >> 4)) ^ (row & 7);
        bf16x8 bk = *(const bf16x8*)&Kl[row*64 + c*8];
        z = __builtin_amdgcn_mfma_f32_16x16x32_bf16(aq[hh], bk, z, 0, 0, 0);
      }
      s[kt] = z;
    }

    // online softmax (row stats live redundantly in all 16 lanes of a group)
    float nm[4], fac[4];
    #pragma unroll
    for (int i = 0; i < 4; i++) {
      float mx = fmaxf(fmaxf(s[0][i], s[1][i]), fmaxf(s[2][i], s[3][i]));
      mx = fmaxf(mx, __shfl_xor(mx, 1));
      mx = fmaxf(mx, __shfl_xor(mx, 2));
      mx = fmaxf(mx, __shfl_xor(mx, 4));
      mx = fmaxf(mx, __shfl_xor(mx, 8));
      float m2 = fmaxf(mrow[i], mx);
      nm[i] = m2;
      fac[i] = __expf(mrow[i] - m2);
      mrow[i] = m2;
    }
    #pragma unroll
    for (int kt = 0; kt < 4; kt++)
      #pragma unroll
      for (int i = 0; i < 4; i++)
        s[kt][i] = __expf(s[kt][i] - nm[i]);
    #pragma unroll
    for (int i = 0; i < 4; i++) {
      float su = s[0][i] + s[1][i] + s[2][i] + s[3][i];
      su += __shfl_xor(su, 1);
      su += __shfl_xor(su, 2);
      su += __shfl_xor(su, 4);
      su += __shfl_xor(su, 8);
      lrow[i] = lrow[i]*fac[i] + su;
    }
    #pragma unroll
    for (int nt = 0; nt < 4; nt++)
      #pragma unroll
      for (int i = 0; i < 4; i++)
        oacc[nt][i] *= fac[i];

    // P (C-layout) -> LDS -> re-read as MFMA A-fragments
    u16* pw = &Pl[w][0];
    #pragma unroll
    for (int kt = 0; kt < 4; kt++)
      #pragma unroll
      for (int i = 0; i < 4; i++)
        pw[((lane >> 4)*4 + i)*72 + kt*16 + (lane & 15)] = f2bf(s[kt][i]);
    __syncthreads();

    // O += P . V   (V^T tile gives b-frag with contiguous keys)
    #pragma unroll
    for (int kh = 0; kh < 2; kh++) {
      bf16x8 ap = *(const bf16x8*)&pw[(lane & 15)*72 + kh*32 + (lane >> 4)*8];
      #pragma unroll
      for (int nt = 0; nt < 4; nt++) {
        int row = nt*16 + (lane & 15);
        int c = (kh*4 + (lane >> 4)) ^ (row & 7);
        bf16x8 bv = *(const bf16x8*)&Vl[row*64 + c*8];
        oacc[nt] = __builtin_amdgcn_mfma_f32_16x16x32_bf16(ap, bv, oacc[nt], 0, 0, 0);
      }
    }
    __syncthreads();
  }

  float rinv[4];
  #pragma unroll
  for (int i = 0; i < 4; i++) rinv[i] = 1.0f / lrow[i];
  #pragma unroll
  for (int nt = 0; nt < 4; nt++)
    #pragma unroll
    for (int ii = 0; ii < 4; ii++) {
      int row = q0 + (lane >> 4)*4 + ii;
      int col = h*64 + nt*16 + (lane & 15);
      O[(b*S_ + row)*D_ + col] = f2bf(oacc[nt][ii] * rinv[ii]);
    }
}

extern "C" void kernel_launch(void* const* d_in, const int* in_sizes, int n_in,
                              void* d_out, int out_size, void* d_ws, size_t ws_size,
                              hipStream_t stream) {
  (void)in_sizes; (void)n_in; (void)out_size; (void)ws_size;
  const float* x  = (const float*)d_in[0];
  const float* Wq = (const float*)d_in[1];
  const float* bq = (const float*)d_in[2];
  const float* Wk = (const float*)d_in[3];
  const float* bk = (const float*)d_in[4];
  const float* Wv = (const float*)d_in[5];
  const float* bv = (const float*)d_in[6];
  const float* Wo = (const float*)d_in[7];
  const float* bo = (const float*)d_in[8];

  char* ws = (char*)d_ws;
  u16* xb  = (u16*)ws;                              // 8,388,608 B (aliased by Ob later)
  u16* wtq = (u16*)(ws + 8388608);                  // 4 x 524,288 B
  u16* wtk = wtq + 512*512;
  u16* wtv = wtk + 512*512;
  u16* wto = wtv + 512*512;
  u16* Qh  = (u16*)(ws + 8388608 + 4*524288);       // 3 x 8,388,608 B
  u16* Kh  = Qh + M_*D_;
  u16* Vt  = Kh + M_*D_;
  u16* Ob  = xb;  // x is dead after the V projection; reuse its buffer

  k_cvt<<<4096, 256, 0, stream>>>(x, xb, M_*D_/4);
  k_twt<<<dim3(16,16,4), dim3(32,8), 0, stream>>>(Wq, Wk, Wv, Wo, wtq, wtk, wtv, wto);
  // Q pre-scaled by 1/sqrt(DH)=0.125 (exact power-of-two scale in bf16)
  k_gemm<<<dim3(4,64), 512, 0, stream>>>(xb, wtq, bq, Qh, 0.125f, 0);
  k_gemm<<<dim3(4,64), 512, 0, stream>>>(xb, wtk, bk, Kh, 1.0f,   0);
  k_gemm<<<dim3(4,64), 512, 0, stream>>>(xb, wtv, bv, Vt, 1.0f,   1);
  k_attn<<<dim3(S_/128, H_, B_), 512, 0, stream>>>(Qh, Kh, Vt, Ob);
  k_gemm<<<dim3(4,64), 512, 0, stream>>>(Ob, wto, bo, d_out, 1.0f, 2);
}

// Round 2
// 268.026 us; speedup vs baseline: 1.2608x; 1.2608x over previous
//
#include <hip/hip_runtime.h>
#include <stdint.h>

#define B_ 2
#define S_ 4096
#define D_ 512
#define H_ 8
#define DH_ 64
#define M_ (B_*S_)   // 8192
#define LOG2E 1.4426950408889634f

typedef unsigned short u16;
typedef __bf16 bf16x8 __attribute__((ext_vector_type(8)));
typedef float f32x4 __attribute__((ext_vector_type(4)));

__device__ __forceinline__ u16 f2bf(float f) {
  unsigned u = __float_as_uint(f);
  u += 0x7fffu + ((u >> 16) & 1u);
  return (u16)(u >> 16);
}

// global -> LDS direct copy, 16B per lane; LDS dest = wave-uniform base + lane*16
__device__ __forceinline__ void gl_lds16(const void* g, void* l) {
  __builtin_amdgcn_global_load_lds(
      (__attribute__((address_space(1))) void*)(void*)g,
      (__attribute__((address_space(3))) void*)l, 16, 0, 0);
}

// ---------------- x fp32 -> bf16 ----------------
__global__ void k_cvt(const float* __restrict__ x, u16* __restrict__ xb, int n4) {
  int i = blockIdx.x * 256 + threadIdx.x;
  if (i < n4) {
    float4 v = ((const float4*)x)[i];
    uint2 p;
    p.x = (unsigned)f2bf(v.x) | ((unsigned)f2bf(v.y) << 16);
    p.y = (unsigned)f2bf(v.z) | ((unsigned)f2bf(v.w) << 16);
    ((uint2*)xb)[i] = p;
  }
}

// ---------------- W [K,N] fp32 -> Wt [N,K] bf16 (tile transpose) ----------------
__global__ void k_twt(const float* __restrict__ w0, const float* __restrict__ w1,
                      const float* __restrict__ w2, const float* __restrict__ w3,
                      u16* __restrict__ t0, u16* __restrict__ t1,
                      u16* __restrict__ t2, u16* __restrict__ t3) {
  __shared__ float t[32][33];
  int z = blockIdx.z;
  const float* w = z == 0 ? w0 : z == 1 ? w1 : z == 2 ? w2 : w3;
  u16* wt       = z == 0 ? t0 : z == 1 ? t1 : z == 2 ? t2 : t3;
  int n0 = blockIdx.x * 32, k0 = blockIdx.y * 32;
  int tx = threadIdx.x, ty = threadIdx.y;  // 32 x 8
  #pragma unroll
  for (int j = 0; j < 4; j++) t[ty + 8*j][tx] = w[(k0 + ty + 8*j) * D_ + n0 + tx];
  __syncthreads();
  #pragma unroll
  for (int j = 0; j < 4; j++) wt[(n0 + ty + 8*j) * D_ + k0 + tx] = f2bf(t[tx][ty + 8*j]);
}

// ---------------- GEMM body: C[m,n] = relu(A[m,:] . Bt[n,:] + bias[n]) * scale ----------------
// mode 0: bf16 out [B,H,S,DH]; mode 1: bf16 out [B,H,DH,S] (packed b64 stores);
// mode 2: f32 out [M_,D_].
__device__ __forceinline__
void gemm_body(const u16* __restrict__ A, const u16* __restrict__ Bt,
               const float* __restrict__ bias, void* __restrict__ out,
               float scale, int mode) {
  __shared__ __align__(16) u16 Al[128*64];
  __shared__ __align__(16) u16 Bl[128*64];
  int tid = threadIdx.x;
  int lane = tid & 63, w = tid >> 6;     // 8 waves: 2 (m) x 4 (n)
  int wr = w >> 2, wc = w & 3;
  int g = lane >> 4, qi = lane & 15;
  int m0 = blockIdx.y * 128, n0 = blockIdx.x * 128;
  int swzc = ((lane & 7) ^ (lane >> 3)) * 8;
  int lr8 = lane >> 3;

  f32x4 acc[4][2] = {};

  for (int k0 = 0; k0 < D_; k0 += 64) {
    #pragma unroll
    for (int j = 0; j < 2; j++) {
      int r0 = (w*2 + j) * 8;
      gl_lds16(A  + (m0 + r0 + lr8) * D_ + k0 + swzc, &Al[r0 * 64]);
      gl_lds16(Bt + (n0 + r0 + lr8) * D_ + k0 + swzc, &Bl[r0 * 64]);
    }
    __syncthreads();
    #pragma unroll
    for (int h = 0; h < 2; h++) {
      bf16x8 a[4], bq[2];
      #pragma unroll
      for (int i = 0; i < 4; i++) {
        int row = wr*64 + i*16 + qi;
        int c = (h*4 + g) ^ (row & 7);
        a[i] = *(const bf16x8*)&Al[row*64 + c*8];
      }
      #pragma unroll
      for (int jn = 0; jn < 2; jn++) {
        int row = wc*32 + jn*16 + qi;
        int c = (h*4 + g) ^ (row & 7);
        bq[jn] = *(const bf16x8*)&Bl[row*64 + c*8];
      }
      #pragma unroll
      for (int i = 0; i < 4; i++)
        #pragma unroll
        for (int jn = 0; jn < 2; jn++)
          acc[i][jn] = __builtin_amdgcn_mfma_f32_16x16x32_bf16(a[i], bq[jn], acc[i][jn], 0, 0, 0);
    }
    __syncthreads();
  }

  #pragma unroll
  for (int i = 0; i < 4; i++)
    #pragma unroll
    for (int jn = 0; jn < 2; jn++) {
      int col = n0 + wc*32 + jn*16 + qi;
      float bs = bias[col];
      if (mode == 1) {
        // V^T: pack 4 consecutive ss into one 8B store
        int row0 = m0 + wr*64 + i*16 + g*4;
        int bb = row0 >> 12, ss0 = row0 & (S_ - 1);
        int hh = col >> 6, dd = col & 63;
        ushort4 pk;
        float v0 = fmaxf(acc[i][jn][0] + bs, 0.0f) * scale;
        float v1 = fmaxf(acc[i][jn][1] + bs, 0.0f) * scale;
        float v2 = fmaxf(acc[i][jn][2] + bs, 0.0f) * scale;
        float v3 = fmaxf(acc[i][jn][3] + bs, 0.0f) * scale;
        pk.x = f2bf(v0); pk.y = f2bf(v1); pk.z = f2bf(v2); pk.w = f2bf(v3);
        *(ushort4*)&((u16*)out)[((bb*H_ + hh)*DH_ + dd)*S_ + ss0] = pk;
      } else {
        #pragma unroll
        for (int ii = 0; ii < 4; ii++) {
          int row = m0 + wr*64 + i*16 + g*4 + ii;
          float v = fmaxf(acc[i][jn][ii] + bs, 0.0f) * scale;
          if (mode == 2) {
            ((float*)out)[row * D_ + col] = v;
          } else {
            int bb = row >> 12, ss = row & (S_ - 1);
            int hh = col >> 6, dd = col & 63;
            ((u16*)out)[((bb*H_ + hh)*S_ + ss)*DH_ + dd] = f2bf(v);
          }
        }
      }
    }
}

__global__ __launch_bounds__(512, 2)
void k_qkv(const u16* __restrict__ A,
           const u16* __restrict__ btq, const u16* __restrict__ btk, const u16* __restrict__ btv,
           const float* __restrict__ bq, const float* __restrict__ bk, const float* __restrict__ bv,
           u16* __restrict__ q, u16* __restrict__ k, u16* __restrict__ v) {
  int z = blockIdx.z;
  if (z == 0)      gemm_body(A, btq, bq, q, 0.125f * LOG2E, 0);  // Q pre-scaled: 1/sqrt(DH) * log2(e)
  else if (z == 1) gemm_body(A, btk, bk, k, 1.0f, 0);
  else             gemm_body(A, btv, bv, v, 1.0f, 1);
}

__global__ __launch_bounds__(512, 2)
void k_go(const u16* __restrict__ A, const u16* __restrict__ bt,
          const float* __restrict__ bias, float* __restrict__ out) {
  gemm_body(A, bt, bias, out, 1.0f, 2);
}

// ---------------- flash attention (swapped QK^T, lane-local softmax) ----------------
// Q: [B,H,S,64] bf16 (pre-scaled by log2e/8), K: [B,H,S,64] bf16, Vt: [B,H,64,S] bf16.
// O: [B,S,512] bf16. Block = 4 waves x 16 q-rows (64 q/block), KV tile 64, K/V dbuf.
__global__ __launch_bounds__(256, 4)
void k_attn(const u16* __restrict__ Q, const u16* __restrict__ K,
            const u16* __restrict__ Vt, u16* __restrict__ O) {
  __shared__ __align__(16) u16 Kl[2][64*64];   // [buf][key][dh]
  __shared__ __align__(16) u16 Vl[2][64*64];   // [buf][dh][key]
  __shared__ __align__(16) u16 Pl[4][16*64];   // per-wave [q][key], chunk-swizzled
  int tid = threadIdx.x;
  int lane = tid & 63, w = tid >> 6;
  int g = lane >> 4, qi = lane & 15;

  // XCD head-affinity: each XCD (bid&7) owns 2 (b,h) pairs -> K/V (2MB) L2-resident
  int bid = blockIdx.x;
  int xcd = bid & 7, idx = bid >> 3;           // idx 0..127
  int hb = xcd * 2 + (idx & 1);                // 0..15
  int qt = idx >> 1;                           // 0..63
  int b = hb >> 3, h = hb & 7;

  const u16* Qh = Q  + ((b*H_ + h) * S_) * DH_;
  const u16* Kh = K  + ((b*H_ + h) * S_) * DH_;
  const u16* Vh = Vt + ((b*H_ + h) * DH_) * S_;
  int q0 = qt*64 + w*16;

  bf16x8 aq[2];
  #pragma unroll
  for (int kh = 0; kh < 2; kh++)
    aq[kh] = *(const bf16x8*)&Qh[(q0 + qi)*DH_ + kh*32 + g*8];

  f32x4 oacc[4] = {};
  float mrow = -1e30f, lrow = 0.0f;            // stats for q = qi (replicated x4 g-groups)

  int swzc = ((lane & 7) ^ (lane >> 3)) * 8;
  int lr8 = lane >> 3;
  u16* Plw = &Pl[w][0];

  // prologue: stage tile 0 -> buf 0 (4 gl_lds16 per wave)
  #pragma unroll
  for (int j = 0; j < 2; j++) {
    int r0 = w*16 + j*8;
    gl_lds16(Kh + (r0 + lr8)*DH_ + swzc, &Kl[0][r0*64]);
    gl_lds16(Vh + (r0 + lr8)*S_ + swzc, &Vl[0][r0*64]);
  }

  const int NT = S_/64;
  for (int t = 0; t < NT; ++t) {
    int buf = t & 1;
    if (t + 1 < NT) {
      int kv0 = (t+1)*64;
      #pragma unroll
      for (int j = 0; j < 2; j++) {
        int r0 = w*16 + j*8;
        gl_lds16(Kh + (kv0 + r0 + lr8)*DH_ + swzc, &Kl[buf^1][r0*64]);
        gl_lds16(Vh + (r0 + lr8)*S_ + kv0 + swzc, &Vl[buf^1][r0*64]);
      }
      asm volatile("s_waitcnt vmcnt(4)" ::: "memory");  // tile t staged (4 newest in flight)
    } else {
      asm volatile("s_waitcnt vmcnt(0)" ::: "memory");
    }
    __builtin_amdgcn_s_barrier();
    __builtin_amdgcn_sched_barrier(0);

    const u16* Kb = &Kl[buf][0];
    const u16* Vb = &Vl[buf][0];

    // S^T = mfma(A=K, B=Q): lane holds S[key][q=qi], keys kt*16 + g*4 + i
    f32x4 s[4];
    #pragma unroll
    for (int kt = 0; kt < 4; kt++) {
      int row = kt*16 + qi;
      f32x4 z = {0.f, 0.f, 0.f, 0.f};
      #pragma unroll
      for (int kh = 0; kh < 2; kh++) {
        int c = (kh*4 + g) ^ (qi & 7);
        bf16x8 ak = *(const bf16x8*)&Kb[row*64 + c*8];
        z = __builtin_amdgcn_mfma_f32_16x16x32_bf16(ak, aq[kh], z, 0, 0, 0);
      }
      s[kt] = z;
    }

    // lane-local row max (16 vals) + 2-shfl combine across g-groups
    float pm = -1e30f;
    #pragma unroll
    for (int kt = 0; kt < 4; kt++)
      #pragma unroll
      for (int i = 0; i < 4; i++) pm = fmaxf(pm, s[kt][i]);
    pm = fmaxf(pm, __shfl_xor(pm, 16));
    pm = fmaxf(pm, __shfl_xor(pm, 32));

    // defer-max: rescale only if some row grew by > 8 (base-2 units; P <= 2^8)
    if (__any(pm > mrow + 8.0f)) {
      float m2 = fmaxf(mrow, pm);
      float fac = exp2f(mrow - m2);
      mrow = m2;
      lrow *= fac;
      float fr[4];
      #pragma unroll
      for (int i = 0; i < 4; i++) fr[i] = __shfl(fac, g*4 + i);
      #pragma unroll
      for (int nt = 0; nt < 4; nt++)
        #pragma unroll
        for (int i = 0; i < 4; i++) oacc[nt][i] *= fr[i];
    }

    // P = 2^(s - m), local sum + 2-shfl combine; pack 4 consecutive keys -> b64
    float sum = 0.0f;
    #pragma unroll
    for (int kt = 0; kt < 4; kt++) {
      float p0 = exp2f(s[kt][0] - mrow); sum += p0;
      float p1 = exp2f(s[kt][1] - mrow); sum += p1;
      float p2 = exp2f(s[kt][2] - mrow); sum += p2;
      float p3 = exp2f(s[kt][3] - mrow); sum += p3;
      ushort4 pk;
      pk.x = f2bf(p0); pk.y = f2bf(p1); pk.z = f2bf(p2); pk.w = f2bf(p3);
      int c = (kt*2 + (g >> 1)) ^ (qi & 7);
      *(ushort4*)&Plw[qi*64 + c*8 + (g & 1)*4] = pk;
    }
    sum += __shfl_xor(sum, 16);
    sum += __shfl_xor(sum, 32);
    lrow += sum;

    // O += P . V  (P per-wave, no barrier needed; V^T tile gives B-frag)
    #pragma unroll
    for (int kh = 0; kh < 2; kh++) {
      int cA = (kh*4 + g) ^ (qi & 7);
      bf16x8 ap = *(const bf16x8*)&Plw[qi*64 + cA*8];
      #pragma unroll
      for (int nt = 0; nt < 4; nt++) {
        int row = nt*16 + qi;
        bf16x8 bv = *(const bf16x8*)&Vb[row*64 + cA*8];
        oacc[nt] = __builtin_amdgcn_mfma_f32_16x16x32_bf16(ap, bv, oacc[nt], 0, 0, 0);
      }
    }
    __builtin_amdgcn_sched_barrier(0);
    __builtin_amdgcn_s_barrier();   // protect cur buf from next iter's staging
  }

  float rv = 1.0f / lrow;
  float rr[4];
  #pragma unroll
  for (int i = 0; i < 4; i++) rr[i] = __shfl(rv, g*4 + i);
  #pragma unroll
  for (int nt = 0; nt < 4; nt++)
    #pragma unroll
    for (int ii = 0; ii < 4; ii++) {
      int row = q0 + g*4 + ii;
      int col = h*64 + nt*16 + qi;
      O[(b*S_ + row)*D_ + col] = f2bf(oacc[nt][ii] * rr[ii]);
    }
}

extern "C" void kernel_launch(void* const* d_in, const int* in_sizes, int n_in,
                              void* d_out, int out_size, void* d_ws, size_t ws_size,
                              hipStream_t stream) {
  (void)in_sizes; (void)n_in; (void)out_size; (void)ws_size;
  const float* x  = (const float*)d_in[0];
  const float* Wq = (const float*)d_in[1];
  const float* bq = (const float*)d_in[2];
  const float* Wk = (const float*)d_in[3];
  const float* bk = (const float*)d_in[4];
  const float* Wv = (const float*)d_in[5];
  const float* bv = (const float*)d_in[6];
  const float* Wo = (const float*)d_in[7];
  const float* bo = (const float*)d_in[8];

  char* ws = (char*)d_ws;
  u16* xb  = (u16*)ws;                              // 8 MB (reused as Ob after attn)
  u16* wtq = (u16*)(ws + 8388608);                  // 4 x 512 KB
  u16* wtk = wtq + 512*512;
  u16* wtv = wtk + 512*512;
  u16* wto = wtv + 512*512;
  u16* Qh  = (u16*)(ws + 8388608 + 4*524288);       // 3 x 8 MB
  u16* Kh  = Qh + M_*D_;
  u16* Vt  = Kh + M_*D_;
  u16* Ob  = xb;

  k_cvt<<<4096, 256, 0, stream>>>(x, xb, M_*D_/4);
  k_twt<<<dim3(16,16,4), dim3(32,8), 0, stream>>>(Wq, Wk, Wv, Wo, wtq, wtk, wtv, wto);
  k_qkv<<<dim3(4,64,3), 512, 0, stream>>>(xb, wtq, wtk, wtv, bq, bk, bv, Qh, Kh, Vt);
  k_attn<<<1024, 256, 0, stream>>>(Qh, Kh, Vt, Ob);
  k_go<<<dim3(4,64), 512, 0, stream>>>(Ob, wto, bo, (float*)d_out);
}

// Round 4
// 267.087 us; speedup vs baseline: 1.2653x; 1.0035x over previous
//
#include <hip/hip_runtime.h>
#include <stdint.h>

#define B_ 2
#define S_ 4096
#define D_ 512
#define H_ 8
#define DH_ 64
#define M_ (B_*S_)   // 8192
#define LOG2E 1.4426950408889634f

typedef unsigned short u16;
typedef __bf16 bf16x8 __attribute__((ext_vector_type(8)));
typedef __bf16 bf16x4 __attribute__((ext_vector_type(4)));
typedef float f32x4 __attribute__((ext_vector_type(4)));

// f32 -> bf16 via compiler-native cast (RNE; lowers to HW cvt on gfx950)
__device__ __forceinline__ u16 f2bf(float f) {
  __bf16 b = (__bf16)f;
  return __builtin_bit_cast(u16, b);
}

// global -> LDS direct copy, 16B per lane; LDS dest = wave-uniform base + lane*16
__device__ __forceinline__ void gl_lds16(const void* g, void* l) {
  __builtin_amdgcn_global_load_lds(
      (__attribute__((address_space(1))) void*)(void*)g,
      (__attribute__((address_space(3))) void*)l, 16, 0, 0);
}

// ---------------- x fp32 -> bf16 ----------------
__global__ void k_cvt(const float* __restrict__ x, u16* __restrict__ xb, int n4) {
  int i = blockIdx.x * 256 + threadIdx.x;
  if (i < n4) {
    float4 v = ((const float4*)x)[i];
    bf16x4 o;
    o[0] = (__bf16)v.x; o[1] = (__bf16)v.y; o[2] = (__bf16)v.z; o[3] = (__bf16)v.w;
    ((bf16x4*)xb)[i] = o;
  }
}

// ---------------- W [K,N] fp32 -> Wt [N,K] bf16 (tile transpose) ----------------
__global__ void k_twt(const float* __restrict__ w0, const float* __restrict__ w1,
                      const float* __restrict__ w2, const float* __restrict__ w3,
                      u16* __restrict__ t0, u16* __restrict__ t1,
                      u16* __restrict__ t2, u16* __restrict__ t3) {
  __shared__ float t[32][33];
  int z = blockIdx.z;
  const float* w = z == 0 ? w0 : z == 1 ? w1 : z == 2 ? w2 : w3;
  u16* wt       = z == 0 ? t0 : z == 1 ? t1 : z == 2 ? t2 : t3;
  int n0 = blockIdx.x * 32, k0 = blockIdx.y * 32;
  int tx = threadIdx.x, ty = threadIdx.y;  // 32 x 8
  #pragma unroll
  for (int j = 0; j < 4; j++) t[ty + 8*j][tx] = w[(k0 + ty + 8*j) * D_ + n0 + tx];
  __syncthreads();
  #pragma unroll
  for (int j = 0; j < 4; j++) wt[(n0 + ty + 8*j) * D_ + k0 + tx] = f2bf(t[tx][ty + 8*j]);
}

// ---------------- GEMM body: C[m,n] = relu(A[m,:] . Bt[n,:] + bias[n]) * scale ----------------
// mode 0: bf16 out [B,H,S,DH]; mode 1: bf16 out [B,H,DH,S] (packed b64 stores);
// mode 2: f32 out [M_,D_].
__device__ __forceinline__
void gemm_body(const u16* __restrict__ A, const u16* __restrict__ Bt,
               const float* __restrict__ bias, void* __restrict__ out,
               float scale, int mode) {
  __shared__ __align__(16) u16 Al[128*64];
  __shared__ __align__(16) u16 Bl[128*64];
  int tid = threadIdx.x;
  int lane = tid & 63, w = tid >> 6;     // 8 waves: 2 (m) x 4 (n)
  int wr = w >> 2, wc = w & 3;
  int g = lane >> 4, qi = lane & 15;
  int m0 = blockIdx.y * 128, n0 = blockIdx.x * 128;
  int swzc = ((lane & 7) ^ (lane >> 3)) * 8;
  int lr8 = lane >> 3;

  f32x4 acc[4][2] = {};

  for (int k0 = 0; k0 < D_; k0 += 64) {
    #pragma unroll
    for (int j = 0; j < 2; j++) {
      int r0 = (w*2 + j) * 8;
      gl_lds16(A  + (m0 + r0 + lr8) * D_ + k0 + swzc, &Al[r0 * 64]);
      gl_lds16(Bt + (n0 + r0 + lr8) * D_ + k0 + swzc, &Bl[r0 * 64]);
    }
    __syncthreads();
    #pragma unroll
    for (int h = 0; h < 2; h++) {
      bf16x8 a[4], bq[2];
      #pragma unroll
      for (int i = 0; i < 4; i++) {
        int row = wr*64 + i*16 + qi;
        int c = (h*4 + g) ^ (row & 7);
        a[i] = *(const bf16x8*)&Al[row*64 + c*8];
      }
      #pragma unroll
      for (int jn = 0; jn < 2; jn++) {
        int row = wc*32 + jn*16 + qi;
        int c = (h*4 + g) ^ (row & 7);
        bq[jn] = *(const bf16x8*)&Bl[row*64 + c*8];
      }
      #pragma unroll
      for (int i = 0; i < 4; i++)
        #pragma unroll
        for (int jn = 0; jn < 2; jn++)
          acc[i][jn] = __builtin_amdgcn_mfma_f32_16x16x32_bf16(a[i], bq[jn], acc[i][jn], 0, 0, 0);
    }
    __syncthreads();
  }

  #pragma unroll
  for (int i = 0; i < 4; i++)
    #pragma unroll
    for (int jn = 0; jn < 2; jn++) {
      int col = n0 + wc*32 + jn*16 + qi;
      float bs = bias[col];
      if (mode == 1) {
        // V^T: pack 4 consecutive ss into one 8B store
        int row0 = m0 + wr*64 + i*16 + g*4;
        int bb = row0 >> 12, ss0 = row0 & (S_ - 1);
        int hh = col >> 6, dd = col & 63;
        bf16x4 pk;
        pk[0] = (__bf16)(fmaxf(acc[i][jn][0] + bs, 0.0f) * scale);
        pk[1] = (__bf16)(fmaxf(acc[i][jn][1] + bs, 0.0f) * scale);
        pk[2] = (__bf16)(fmaxf(acc[i][jn][2] + bs, 0.0f) * scale);
        pk[3] = (__bf16)(fmaxf(acc[i][jn][3] + bs, 0.0f) * scale);
        *(bf16x4*)&((u16*)out)[((bb*H_ + hh)*DH_ + dd)*S_ + ss0] = pk;
      } else {
        #pragma unroll
        for (int ii = 0; ii < 4; ii++) {
          int row = m0 + wr*64 + i*16 + g*4 + ii;
          float v = fmaxf(acc[i][jn][ii] + bs, 0.0f) * scale;
          if (mode == 2) {
            ((float*)out)[row * D_ + col] = v;
          } else {
            int bb = row >> 12, ss = row & (S_ - 1);
            int hh = col >> 6, dd = col & 63;
            ((u16*)out)[((bb*H_ + hh)*S_ + ss)*DH_ + dd] = f2bf(v);
          }
        }
      }
    }
}

__global__ __launch_bounds__(512, 2)
void k_qkv(const u16* __restrict__ A,
           const u16* __restrict__ btq, const u16* __restrict__ btk, const u16* __restrict__ btv,
           const float* __restrict__ bq, const float* __restrict__ bk, const float* __restrict__ bv,
           u16* __restrict__ q, u16* __restrict__ k, u16* __restrict__ v) {
  int z = blockIdx.z;
  if (z == 0)      gemm_body(A, btq, bq, q, 0.125f * LOG2E, 0);  // Q pre-scaled: 1/sqrt(DH) * log2(e)
  else if (z == 1) gemm_body(A, btk, bk, k, 1.0f, 0);
  else             gemm_body(A, btv, bv, v, 1.0f, 1);
}

__global__ __launch_bounds__(512, 2)
void k_go(const u16* __restrict__ A, const u16* __restrict__ bt,
          const float* __restrict__ bias, float* __restrict__ out) {
  gemm_body(A, bt, bias, out, 1.0f, 2);
}

// ---------------- flash attention (swapped QK^T, -m folded into MFMA C-in) ----------------
// Q: [B,H,S,64] bf16 (pre-scaled by log2e/8), K: [B,H,S,64] bf16, Vt: [B,H,64,S] bf16.
// O: [B,S,512] bf16. Block = 4 waves x 16 q-rows, KV tile 64, K/V dbuf, vmcnt(4).
// m starts at 0; logits (base-2) are bounded (~<6) so the defer-rescale (THR=8)
// almost never fires -> fast path has no subtracts and no rescale.
__global__ __launch_bounds__(256, 4)
void k_attn(const u16* __restrict__ Q, const u16* __restrict__ K,
            const u16* __restrict__ Vt, u16* __restrict__ O) {
  __shared__ __align__(16) u16 Kl[2][64*64];   // [buf][key][dh]
  __shared__ __align__(16) u16 Vl[2][64*64];   // [buf][dh][key]
  __shared__ __align__(16) u16 Pl[4][16*64];   // per-wave [q][key], chunk-swizzled
  int tid = threadIdx.x;
  int lane = tid & 63, w = tid >> 6;
  int g = lane >> 4, qi = lane & 15;

  // XCD head-affinity: each XCD (bid&7) owns 2 (b,h) pairs -> K/V (2MB) L2-resident
  int bid = blockIdx.x;
  int xcd = bid & 7, idx = bid >> 3;           // idx 0..127
  int hb = xcd * 2 + (idx & 1);                // 0..15
  int qt = idx >> 1;                           // 0..63
  int b = hb >> 3, h = hb & 7;

  const u16* Qh = Q  + ((b*H_ + h) * S_) * DH_;
  const u16* Kh = K  + ((b*H_ + h) * S_) * DH_;
  const u16* Vh = Vt + ((b*H_ + h) * DH_) * S_;
  int q0 = qt*64 + w*16;

  bf16x8 aq[2];
  #pragma unroll
  for (int kh = 0; kh < 2; kh++)
    aq[kh] = *(const bf16x8*)&Qh[(q0 + qi)*DH_ + kh*32 + g*8];

  f32x4 oacc[4] = {};
  float lrow = 0.0f;                   // denom for q = qi (replicated x4 g-groups)
  float nmr = 0.0f;                    // -(running max), starts at 0
  f32x4 nmr4 = {0.f, 0.f, 0.f, 0.f};  // hoisted C-init splat of nmr

  int swzc = ((lane & 7) ^ (lane >> 3)) * 8;
  int lr8 = lane >> 3;
  u16* Plw = &Pl[w][0];

  // prologue: stage tile 0 -> buf 0 (4 gl_lds16 per wave)
  #pragma unroll
  for (int j = 0; j < 2; j++) {
    int r0 = w*16 + j*8;
    gl_lds16(Kh + (r0 + lr8)*DH_ + swzc, &Kl[0][r0*64]);
    gl_lds16(Vh + (r0 + lr8)*S_ + swzc, &Vl[0][r0*64]);
  }

  const int NT = S_/64;
  for (int t = 0; t < NT; ++t) {
    int buf = t & 1;
    if (t + 1 < NT) {
      int kv0 = (t+1)*64;
      #pragma unroll
      for (int j = 0; j < 2; j++) {
        int r0 = w*16 + j*8;
        gl_lds16(Kh + (kv0 + r0 + lr8)*DH_ + swzc, &Kl[buf^1][r0*64]);
        gl_lds16(Vh + (r0 + lr8)*S_ + kv0 + swzc, &Vl[buf^1][r0*64]);
      }
      asm volatile("s_waitcnt vmcnt(4)" ::: "memory");  // tile t staged (4 newest in flight)
    } else {
      asm volatile("s_waitcnt vmcnt(0)" ::: "memory");
    }
    __builtin_amdgcn_s_barrier();
    __builtin_amdgcn_sched_barrier(0);

    const u16* Kb = &Kl[buf][0];
    const u16* Vb = &Vl[buf][0];

    // S' = K.Q^T - m : C-init = -m (all 16 scores of a lane share q = qi)
    // lane holds S'[key = kt*16 + g*4 + i][q = qi]
    f32x4 s[4];
    #pragma unroll
    for (int kt = 0; kt < 4; kt++) {
      int row = kt*16 + qi;
      int c0 = (0*4 + g) ^ (qi & 7);
      int c1 = (1*4 + g) ^ (qi & 7);
      bf16x8 ak0 = *(const bf16x8*)&Kb[row*64 + c0*8];
      bf16x8 ak1 = *(const bf16x8*)&Kb[row*64 + c1*8];
      f32x4 z = __builtin_amdgcn_mfma_f32_16x16x32_bf16(ak0, aq[0], nmr4, 0, 0, 0);
      s[kt] = __builtin_amdgcn_mfma_f32_16x16x32_bf16(ak1, aq[1], z, 0, 0, 0);
    }

    // row max of s' (16 lane-local) + 2-shfl combine across g-groups
    float pm = fmaxf(fmaxf(s[0][0], s[0][1]), fmaxf(s[0][2], s[0][3]));
    #pragma unroll
    for (int kt = 1; kt < 4; kt++) {
      float m01 = fmaxf(s[kt][0], s[kt][1]);
      float m23 = fmaxf(s[kt][2], s[kt][3]);
      pm = fmaxf(pm, fmaxf(m01, m23));
    }
    pm = fmaxf(pm, __shfl_xor(pm, 16));
    pm = fmaxf(pm, __shfl_xor(pm, 32));

    float sum = 0.0f;
    if (__builtin_expect(__any(pm > 8.0f), 0)) {
      // rare rescale path: shift running max up by d, rescale O and l
      float d = fmaxf(pm, 0.0f);
      float fac = exp2f(-d);
      nmr -= d;
      nmr4[0] = nmr; nmr4[1] = nmr; nmr4[2] = nmr; nmr4[3] = nmr;
      lrow *= fac;
      float fr[4];
      #pragma unroll
      for (int i = 0; i < 4; i++) fr[i] = __shfl(fac, g*4 + i);
      #pragma unroll
      for (int nt = 0; nt < 4; nt++)
        #pragma unroll
        for (int i = 0; i < 4; i++) oacc[nt][i] *= fr[i];
      #pragma unroll
      for (int kt = 0; kt < 4; kt++) {
        float e0 = exp2f(s[kt][0] - d); sum += e0;
        float e1 = exp2f(s[kt][1] - d); sum += e1;
        float e2 = exp2f(s[kt][2] - d); sum += e2;
        float e3 = exp2f(s[kt][3] - d); sum += e3;
        bf16x4 pk;
        pk[0] = (__bf16)e0; pk[1] = (__bf16)e1; pk[2] = (__bf16)e2; pk[3] = (__bf16)e3;
        int c = (kt*2 + (g >> 1)) ^ (qi & 7);
        *(bf16x4*)&Plw[qi*64 + c*8 + (g & 1)*4] = pk;
      }
    } else {
      // fast path: P = 2^s' directly (no subtract, no rescale)
      #pragma unroll
      for (int kt = 0; kt < 4; kt++) {
        float e0 = exp2f(s[kt][0]); sum += e0;
        float e1 = exp2f(s[kt][1]); sum += e1;
        float e2 = exp2f(s[kt][2]); sum += e2;
        float e3 = exp2f(s[kt][3]); sum += e3;
        bf16x4 pk;
        pk[0] = (__bf16)e0; pk[1] = (__bf16)e1; pk[2] = (__bf16)e2; pk[3] = (__bf16)e3;
        int c = (kt*2 + (g >> 1)) ^ (qi & 7);
        *(bf16x4*)&Plw[qi*64 + c*8 + (g & 1)*4] = pk;
      }
    }
    sum += __shfl_xor(sum, 16);
    sum += __shfl_xor(sum, 32);
    lrow += sum;

    // O += P . V  (P per-wave; V^T tile gives B-frag)
    __builtin_amdgcn_s_setprio(1);
    #pragma unroll
    for (int kh = 0; kh < 2; kh++) {
      int cA = (kh*4 + g) ^ (qi & 7);
      bf16x8 ap = *(const bf16x8*)&Plw[qi*64 + cA*8];
      #pragma unroll
      for (int nt = 0; nt < 4; nt++) {
        int row = nt*16 + qi;
        bf16x8 bv = *(const bf16x8*)&Vb[row*64 + cA*8];
        oacc[nt] = __builtin_amdgcn_mfma_f32_16x16x32_bf16(ap, bv, oacc[nt], 0, 0, 0);
      }
    }
    __builtin_amdgcn_s_setprio(0);
    __builtin_amdgcn_sched_barrier(0);
    __builtin_amdgcn_s_barrier();   // protect cur buf from next iter's staging
  }

  float rv = 1.0f / lrow;
  float rr[4];
  #pragma unroll
  for (int i = 0; i < 4; i++) rr[i] = __shfl(rv, g*4 + i);
  #pragma unroll
  for (int nt = 0; nt < 4; nt++)
    #pragma unroll
    for (int ii = 0; ii < 4; ii++) {
      int row = q0 + g*4 + ii;
      int col = h*64 + nt*16 + qi;
      O[(b*S_ + row)*D_ + col] = f2bf(oacc[nt][ii] * rr[ii]);
    }
}

extern "C" void kernel_launch(void* const* d_in, const int* in_sizes, int n_in,
                              void* d_out, int out_size, void* d_ws, size_t ws_size,
                              hipStream_t stream) {
  (void)in_sizes; (void)n_in; (void)out_size; (void)ws_size;
  const float* x  = (const float*)d_in[0];
  const float* Wq = (const float*)d_in[1];
  const float* bq = (const float*)d_in[2];
  const float* Wk = (const float*)d_in[3];
  const float* bk = (const float*)d_in[4];
  const float* Wv = (const float*)d_in[5];
  const float* bv = (const float*)d_in[6];
  const float* Wo = (const float*)d_in[7];
  const float* bo = (const float*)d_in[8];

  char* ws = (char*)d_ws;
  u16* xb  = (u16*)ws;                              // 8 MB (reused as Ob after attn)
  u16* wtq = (u16*)(ws + 8388608);                  // 4 x 512 KB
  u16* wtk = wtq + 512*512;
  u16* wtv = wtk + 512*512;
  u16* wto = wtv + 512*512;
  u16* Qh  = (u16*)(ws + 8388608 + 4*524288);       // 3 x 8 MB
  u16* Kh  = Qh + M_*D_;
  u16* Vt  = Kh + M_*D_;
  u16* Ob  = xb;

  k_cvt<<<4096, 256, 0, stream>>>(x, xb, M_*D_/4);
  k_twt<<<dim3(16,16,4), dim3(32,8), 0, stream>>>(Wq, Wk, Wv, Wo, wtq, wtk, wtv, wto);
  k_qkv<<<dim3(4,64,3), 512, 0, stream>>>(xb, wtq, wtk, wtv, bq, bk, bv, Qh, Kh, Vt);
  k_attn<<<1024, 256, 0, stream>>>(Qh, Kh, Vt, Ob);
  k_go<<<dim3(4,64), 512, 0, stream>>>(Ob, wto, bo, (float*)d_out);
}

// Round 6
// 215.194 us; speedup vs baseline: 1.5704x; 1.2411x over previous
//
#include <hip/hip_runtime.h>
#include <stdint.h>

#define B_ 2
#define S_ 4096
#define D_ 512
#define H_ 8
#define DH_ 64
#define M_ (B_*S_)   // 8192
#define LOG2E 1.4426950408889634f

typedef unsigned short u16;
typedef __bf16 bf16x8 __attribute__((ext_vector_type(8)));
typedef __bf16 bf16x4 __attribute__((ext_vector_type(4)));
typedef float f32x4 __attribute__((ext_vector_type(4)));

#if defined(__has_builtin)
#if __has_builtin(__builtin_amdgcn_exp2f)
#define EXP2(x) __builtin_amdgcn_exp2f(x)
#else
#define EXP2(x) exp2f(x)
#endif
#else
#define EXP2(x) exp2f(x)
#endif

// f32 -> bf16 via compiler-native cast (RNE; lowers to HW cvt on gfx950)
__device__ __forceinline__ u16 f2bf(float f) {
  __bf16 b = (__bf16)f;
  return __builtin_bit_cast(u16, b);
}

// global -> LDS direct copy, 16B per lane; LDS dest = wave-uniform base + lane*16.
// NOTE: imm offset is kept 0 always — R5's offset:1024 variant corrupted LDS
// (offset semantics for LDS-DMA are unverified on gfx950; R6 reverted it).
__device__ __forceinline__ void gl_lds16(const void* g, void* l) {
  __builtin_amdgcn_global_load_lds(
      (__attribute__((address_space(1))) void*)(void*)g,
      (__attribute__((address_space(3))) void*)l, 16, 0, 0);
}

#define MM(a, b, c) __builtin_amdgcn_mfma_f32_16x16x32_bf16((a), (b), (c), 0, 0, 0)
#define LD8(p) (*(const bf16x8*)(p))

// ---------------- x fp32 -> bf16 ----------------
__global__ void k_cvt(const float* __restrict__ x, u16* __restrict__ xb, int n4) {
  int i = blockIdx.x * 256 + threadIdx.x;
  if (i < n4) {
    float4 v = ((const float4*)x)[i];
    bf16x4 o;
    o[0] = (__bf16)v.x; o[1] = (__bf16)v.y; o[2] = (__bf16)v.z; o[3] = (__bf16)v.w;
    ((bf16x4*)xb)[i] = o;
  }
}

// ---------------- W [K,N] fp32 -> Wt [N,K] bf16 (tile transpose) ----------------
__global__ void k_twt(const float* __restrict__ w0, const float* __restrict__ w1,
                      const float* __restrict__ w2, const float* __restrict__ w3,
                      u16* __restrict__ t0, u16* __restrict__ t1,
                      u16* __restrict__ t2, u16* __restrict__ t3) {
  __shared__ float t[32][33];
  int z = blockIdx.z;
  const float* w = z == 0 ? w0 : z == 1 ? w1 : z == 2 ? w2 : w3;
  u16* wt       = z == 0 ? t0 : z == 1 ? t1 : z == 2 ? t2 : t3;
  int n0 = blockIdx.x * 32, k0 = blockIdx.y * 32;
  int tx = threadIdx.x, ty = threadIdx.y;  // 32 x 8
  #pragma unroll
  for (int j = 0; j < 4; j++) t[ty + 8*j][tx] = w[(k0 + ty + 8*j) * D_ + n0 + tx];
  __syncthreads();
  #pragma unroll
  for (int j = 0; j < 4; j++) wt[(n0 + ty + 8*j) * D_ + k0 + tx] = f2bf(t[tx][ty + 8*j]);
}

// ---------------- GEMM body: C[m,n] = relu(A[m,:] . Bt[n,:] + bias[n]) * scale ----------------
// mode 0: bf16 out [B,H,S,DH]; mode 1: bf16 out [B,H,DH,S] (packed b64 stores);
// mode 2: f32 out [M_,D_].
__device__ __forceinline__
void gemm_body(const u16* __restrict__ A, const u16* __restrict__ Bt,
               const float* __restrict__ bias, void* __restrict__ out,
               float scale, int mode) {
  __shared__ __align__(16) u16 Al[128*64];
  __shared__ __align__(16) u16 Bl[128*64];
  int tid = threadIdx.x;
  int lane = tid & 63, w = tid >> 6;     // 8 waves: 2 (m) x 4 (n)
  int wr = w >> 2, wc = w & 3;
  int g = lane >> 4, qi = lane & 15;
  int m0 = blockIdx.y * 128, n0 = blockIdx.x * 128;
  int swzc = ((lane & 7) ^ (lane >> 3)) * 8;
  int lr8 = lane >> 3;

  f32x4 acc[4][2] = {};

  for (int k0 = 0; k0 < D_; k0 += 64) {
    #pragma unroll
    for (int j = 0; j < 2; j++) {
      int r0 = (w*2 + j) * 8;
      gl_lds16(A  + (m0 + r0 + lr8) * D_ + k0 + swzc, &Al[r0 * 64]);
      gl_lds16(Bt + (n0 + r0 + lr8) * D_ + k0 + swzc, &Bl[r0 * 64]);
    }
    __syncthreads();
    #pragma unroll
    for (int h = 0; h < 2; h++) {
      bf16x8 a[4], bq[2];
      #pragma unroll
      for (int i = 0; i < 4; i++) {
        int row = wr*64 + i*16 + qi;
        int c = (h*4 + g) ^ (row & 7);
        a[i] = LD8(&Al[row*64 + c*8]);
      }
      #pragma unroll
      for (int jn = 0; jn < 2; jn++) {
        int row = wc*32 + jn*16 + qi;
        int c = (h*4 + g) ^ (row & 7);
        bq[jn] = LD8(&Bl[row*64 + c*8]);
      }
      #pragma unroll
      for (int i = 0; i < 4; i++)
        #pragma unroll
        for (int jn = 0; jn < 2; jn++)
          acc[i][jn] = MM(a[i], bq[jn], acc[i][jn]);
    }
    __syncthreads();
  }

  #pragma unroll
  for (int i = 0; i < 4; i++)
    #pragma unroll
    for (int jn = 0; jn < 2; jn++) {
      int col = n0 + wc*32 + jn*16 + qi;
      float bs = bias[col];
      if (mode == 1) {
        int row0 = m0 + wr*64 + i*16 + g*4;
        int bb = row0 >> 12, ss0 = row0 & (S_ - 1);
        int hh = col >> 6, dd = col & 63;
        bf16x4 pk;
        pk[0] = (__bf16)(fmaxf(acc[i][jn][0] + bs, 0.0f) * scale);
        pk[1] = (__bf16)(fmaxf(acc[i][jn][1] + bs, 0.0f) * scale);
        pk[2] = (__bf16)(fmaxf(acc[i][jn][2] + bs, 0.0f) * scale);
        pk[3] = (__bf16)(fmaxf(acc[i][jn][3] + bs, 0.0f) * scale);
        *(bf16x4*)&((u16*)out)[((bb*H_ + hh)*DH_ + dd)*S_ + ss0] = pk;
      } else {
        #pragma unroll
        for (int ii = 0; ii < 4; ii++) {
          int row = m0 + wr*64 + i*16 + g*4 + ii;
          float v = fmaxf(acc[i][jn][ii] + bs, 0.0f) * scale;
          if (mode == 2) {
            ((float*)out)[row * D_ + col] = v;
          } else {
            int bb = row >> 12, ss = row & (S_ - 1);
            int hh = col >> 6, dd = col & 63;
            ((u16*)out)[((bb*H_ + hh)*S_ + ss)*DH_ + dd] = f2bf(v);
          }
        }
      }
    }
}

__global__ __launch_bounds__(512, 2)
void k_qkv(const u16* __restrict__ A,
           const u16* __restrict__ btq, const u16* __restrict__ btk, const u16* __restrict__ btv,
           const float* __restrict__ bq, const float* __restrict__ bk, const float* __restrict__ bv,
           u16* __restrict__ q, u16* __restrict__ k, u16* __restrict__ v) {
  int z = blockIdx.z;
  if (z == 0)      gemm_body(A, btq, bq, q, 0.125f * LOG2E, 0);  // Q pre-scaled: 1/sqrt(DH) * log2(e)
  else if (z == 1) gemm_body(A, btk, bk, k, 1.0f, 0);
  else             gemm_body(A, btv, bv, v, 1.0f, 1);
}

__global__ __launch_bounds__(512, 2)
void k_go(const u16* __restrict__ A, const u16* __restrict__ bt,
          const float* __restrict__ bias, float* __restrict__ out) {
  gemm_body(A, bt, bias, out, 1.0f, 2);
}

// ---------------- flash attention ----------------
// Swapped QK^T, m == 0 (shift-invariant softmax; base-2 logits bounded ~6 so
// 2^s and the f32 running sum cannot overflow), x2-unrolled KV loop with
// compile-time buf, all LDS offsets hoisted, staging via 4 incremented pointers
// (no imm offsets on global_load_lds — see gl_lds16 note).
// Q: [B,H,S,64] bf16 (pre-scaled by log2e/8), K: [B,H,S,64], Vt: [B,H,64,S].
__global__ __launch_bounds__(256, 4)
void k_attn(const u16* __restrict__ Q, const u16* __restrict__ K,
            const u16* __restrict__ Vt, u16* __restrict__ O) {
  __shared__ __align__(16) u16 Kl[2][64*64];   // [buf][key][dh]
  __shared__ __align__(16) u16 Vl[2][64*64];   // [buf][dh][key]
  __shared__ __align__(16) u16 Pl[4][16*64];   // per-wave [q][key], chunk-swizzled
  const int tid = threadIdx.x;
  const int lane = tid & 63, w = tid >> 6;
  const int g = lane >> 4, qi = lane & 15, qi7 = qi & 7;

  // XCD head-affinity: each XCD (bid&7) owns 2 (b,h) pairs -> K/V L2-resident
  const int bid = blockIdx.x;
  const int xcd = bid & 7, idx = bid >> 3;
  const int hb = xcd * 2 + (idx & 1);
  const int qt = idx >> 1;
  const int b = hb >> 3, h = hb & 7;

  const u16* Qh = Q  + ((b*H_ + h) * S_) * DH_;
  const u16* Kh = K  + ((b*H_ + h) * S_) * DH_;
  const u16* Vh = Vt + ((b*H_ + h) * DH_) * S_;
  const int q0 = qt*64 + w*16;

  const bf16x8 aq0 = LD8(&Qh[(q0 + qi)*DH_ + g*8]);
  const bf16x8 aq1 = LD8(&Qh[(q0 + qi)*DH_ + 32 + g*8]);

  f32x4 oacc0 = {}, oacc1 = {}, oacc2 = {}, oacc3 = {};
  const f32x4 zro = {0.f, 0.f, 0.f, 0.f};
  float lrow = 0.0f;   // per-lane partial denom (reduced across g-groups at end)

  const int swzc = ((lane & 7) ^ (lane >> 3)) * 8;
  const int lr8 = lane >> 3;

  // hoisted LDS byte offsets (loop-invariant)
  int fo[4][2];        // K/V frag: row rt*16+qi, chunk (kh*4+g)^qi7
  #pragma unroll
  for (int rt = 0; rt < 4; rt++)
    #pragma unroll
    for (int kh = 0; kh < 2; kh++)
      fo[rt][kh] = (rt*16 + qi)*128 + (((kh*4 + g) ^ qi7)*16);
  int pw[4];           // P write: row qi, chunk (kt*2+(g>>1))^qi7, half g&1
  #pragma unroll
  for (int kt = 0; kt < 4; kt++)
    pw[kt] = qi*128 + (((kt*2 + (g >> 1)) ^ qi7)*16) + (g & 1)*8;
  const int pr0 = qi*128 + ((g ^ qi7)*16);
  const int pr1 = qi*128 + (((4 + g) ^ qi7)*16);
  char* Pw = (char*)Pl[w];

  // staging pointers (advance by one KV tile per TILE)
  const u16* kp0 = Kh + (w*16 + lr8)*DH_ + swzc;   // K rows w*16 + lr8
  const u16* kp1 = kp0 + 8*DH_;                    // K rows w*16 + 8 + lr8
  const u16* vp0 = Vh + (w*16 + lr8)*S_ + swzc;    // V^T dh rows w*16 + lr8
  const u16* vp1 = vp0 + 8*S_;                     // V^T dh rows w*16 + 8 + lr8
  u16* kdst[2][2];
  u16* vdst[2][2];
  #pragma unroll
  for (int bb2 = 0; bb2 < 2; bb2++)
    #pragma unroll
    for (int j = 0; j < 2; j++) {
      kdst[bb2][j] = &Kl[bb2][(w*16 + j*8)*64];
      vdst[bb2][j] = &Vl[bb2][(w*16 + j*8)*64];
    }

  // prologue: stage tile 0 -> buf 0, advance pointers to tile 1
  gl_lds16(kp0, kdst[0][0]);
  gl_lds16(kp1, kdst[0][1]);
  gl_lds16(vp0, vdst[0][0]);
  gl_lds16(vp1, vdst[0][1]);
  kp0 += 64*DH_; kp1 += 64*DH_; vp0 += 64; vp1 += 64;

#define TILE(BUF, LAST) { \
  if (!(LAST)) { \
    gl_lds16(kp0, kdst[(BUF)^1][0]); \
    gl_lds16(kp1, kdst[(BUF)^1][1]); \
    gl_lds16(vp0, vdst[(BUF)^1][0]); \
    gl_lds16(vp1, vdst[(BUF)^1][1]); \
    kp0 += 64*DH_; kp1 += 64*DH_; vp0 += 64; vp1 += 64; \
    asm volatile("s_waitcnt vmcnt(4)" ::: "memory"); \
  } else { \
    asm volatile("s_waitcnt vmcnt(0)" ::: "memory"); \
  } \
  __builtin_amdgcn_s_barrier(); \
  __builtin_amdgcn_sched_barrier(0); \
  const char* Kb = (const char*)Kl[(BUF)]; \
  const char* Vb = (const char*)Vl[(BUF)]; \
  f32x4 s0, s1, s2, s3; \
  { f32x4 z = MM(LD8(Kb + fo[0][0]), aq0, zro); s0 = MM(LD8(Kb + fo[0][1]), aq1, z); } \
  { f32x4 z = MM(LD8(Kb + fo[1][0]), aq0, zro); s1 = MM(LD8(Kb + fo[1][1]), aq1, z); } \
  { f32x4 z = MM(LD8(Kb + fo[2][0]), aq0, zro); s2 = MM(LD8(Kb + fo[2][1]), aq1, z); } \
  { f32x4 z = MM(LD8(Kb + fo[3][0]), aq0, zro); s3 = MM(LD8(Kb + fo[3][1]), aq1, z); } \
  float e0  = EXP2(s0[0]), e1  = EXP2(s0[1]), e2  = EXP2(s0[2]), e3  = EXP2(s0[3]); \
  float e4  = EXP2(s1[0]), e5  = EXP2(s1[1]), e6  = EXP2(s1[2]), e7  = EXP2(s1[3]); \
  float e8  = EXP2(s2[0]), e9  = EXP2(s2[1]), e10 = EXP2(s2[2]), e11 = EXP2(s2[3]); \
  float e12 = EXP2(s3[0]), e13 = EXP2(s3[1]), e14 = EXP2(s3[2]), e15 = EXP2(s3[3]); \
  { bf16x4 p; p[0]=(__bf16)e0;  p[1]=(__bf16)e1;  p[2]=(__bf16)e2;  p[3]=(__bf16)e3;  *(bf16x4*)(Pw + pw[0]) = p; } \
  { bf16x4 p; p[0]=(__bf16)e4;  p[1]=(__bf16)e5;  p[2]=(__bf16)e6;  p[3]=(__bf16)e7;  *(bf16x4*)(Pw + pw[1]) = p; } \
  { bf16x4 p; p[0]=(__bf16)e8;  p[1]=(__bf16)e9;  p[2]=(__bf16)e10; p[3]=(__bf16)e11; *(bf16x4*)(Pw + pw[2]) = p; } \
  { bf16x4 p; p[0]=(__bf16)e12; p[1]=(__bf16)e13; p[2]=(__bf16)e14; p[3]=(__bf16)e15; *(bf16x4*)(Pw + pw[3]) = p; } \
  lrow += (((e0+e1)+(e2+e3)) + ((e4+e5)+(e6+e7))) + (((e8+e9)+(e10+e11)) + ((e12+e13)+(e14+e15))); \
  __builtin_amdgcn_s_setprio(1); \
  { bf16x8 ap = LD8(Pw + pr0); \
    oacc0 = MM(ap, LD8(Vb + fo[0][0]), oacc0); \
    oacc1 = MM(ap, LD8(Vb + fo[1][0]), oacc1); \
    oacc2 = MM(ap, LD8(Vb + fo[2][0]), oacc2); \
    oacc3 = MM(ap, LD8(Vb + fo[3][0]), oacc3); } \
  { bf16x8 ap = LD8(Pw + pr1); \
    oacc0 = MM(ap, LD8(Vb + fo[0][1]), oacc0); \
    oacc1 = MM(ap, LD8(Vb + fo[1][1]), oacc1); \
    oacc2 = MM(ap, LD8(Vb + fo[2][1]), oacc2); \
    oacc3 = MM(ap, LD8(Vb + fo[3][1]), oacc3); } \
  __builtin_amdgcn_s_setprio(0); \
  __builtin_amdgcn_sched_barrier(0); \
  __builtin_amdgcn_s_barrier(); \
}

  for (int i = 0; i < 31; ++i) {
    TILE(0, 0)
    TILE(1, 0)
  }
  TILE(0, 0)
  TILE(1, 1)
#undef TILE

  // denom: reduce partials across the 4 g-groups once
  lrow += __shfl_xor(lrow, 16);
  lrow += __shfl_xor(lrow, 32);
  float rv = 1.0f / lrow;
  float rr[4];
  #pragma unroll
  for (int i = 0; i < 4; i++) rr[i] = __shfl(rv, g*4 + i);
  #pragma unroll
  for (int ii = 0; ii < 4; ii++) {
    int row = q0 + g*4 + ii;
    u16* orow = O + (b*S_ + row)*D_ + h*64 + qi;
    orow[0]  = f2bf(oacc0[ii] * rr[ii]);
    orow[16] = f2bf(oacc1[ii] * rr[ii]);
    orow[32] = f2bf(oacc2[ii] * rr[ii]);
    orow[48] = f2bf(oacc3[ii] * rr[ii]);
  }
}

extern "C" void kernel_launch(void* const* d_in, const int* in_sizes, int n_in,
                              void* d_out, int out_size, void* d_ws, size_t ws_size,
                              hipStream_t stream) {
  (void)in_sizes; (void)n_in; (void)out_size; (void)ws_size;
  const float* x  = (const float*)d_in[0];
  const float* Wq = (const float*)d_in[1];
  const float* bq = (const float*)d_in[2];
  const float* Wk = (const float*)d_in[3];
  const float* bk = (const float*)d_in[4];
  const float* Wv = (const float*)d_in[5];
  const float* bv = (const float*)d_in[6];
  const float* Wo = (const float*)d_in[7];
  const float* bo = (const float*)d_in[8];

  char* ws = (char*)d_ws;
  u16* xb  = (u16*)ws;                              // 8 MB (reused as Ob after attn)
  u16* wtq = (u16*)(ws + 8388608);                  // 4 x 512 KB
  u16* wtk = wtq + 512*512;
  u16* wtv = wtk + 512*512;
  u16* wto = wtv + 512*512;
  u16* Qh  = (u16*)(ws + 8388608 + 4*524288);       // 3 x 8 MB
  u16* Kh  = Qh + M_*D_;
  u16* Vt  = Kh + M_*D_;
  u16* Ob  = xb;

  k_cvt<<<4096, 256, 0, stream>>>(x, xb, M_*D_/4);
  k_twt<<<dim3(16,16,4), dim3(32,8), 0, stream>>>(Wq, Wk, Wv, Wo, wtq, wtk, wtv, wto);
  k_qkv<<<dim3(4,64,3), 512, 0, stream>>>(xb, wtq, wtk, wtv, bq, bk, bv, Qh, Kh, Vt);
  k_attn<<<1024, 256, 0, stream>>>(Qh, Kh, Vt, Ob);
  k_go<<<dim3(4,64), 512, 0, stream>>>(Ob, wto, bo, (float*)d_out);
}

// Round 8
// 203.653 us; speedup vs baseline: 1.6594x; 1.0567x over previous
//
#include <hip/hip_runtime.h>
#include <stdint.h>

#define B_ 2
#define S_ 4096
#define D_ 512
#define H_ 8
#define DH_ 64
#define M_ (B_*S_)   // 8192
#define LOG2E 1.4426950408889634f

typedef unsigned short u16;
typedef __bf16 bf16x8 __attribute__((ext_vector_type(8)));
typedef __bf16 bf16x4 __attribute__((ext_vector_type(4)));
typedef float f32x4 __attribute__((ext_vector_type(4)));

#if defined(__has_builtin)
#if __has_builtin(__builtin_amdgcn_exp2f)
#define EXP2(x) __builtin_amdgcn_exp2f(x)
#else
#define EXP2(x) exp2f(x)
#endif
#else
#define EXP2(x) exp2f(x)
#endif

// f32 -> bf16 via compiler-native cast (RNE; lowers to HW cvt on gfx950)
__device__ __forceinline__ u16 f2bf(float f) {
  __bf16 b = (__bf16)f;
  return __builtin_bit_cast(u16, b);
}

// global -> LDS direct copy, 16B per lane; LDS dest = wave-uniform base + lane*16.
// NOTE: imm offset MUST stay 0 — R5 showed offset:1024 corrupts LDS on gfx950.
__device__ __forceinline__ void gl_lds16(const void* g, void* l) {
  __builtin_amdgcn_global_load_lds(
      (__attribute__((address_space(1))) void*)(void*)g,
      (__attribute__((address_space(3))) void*)l, 16, 0, 0);
}

#define MM(a, b, c) __builtin_amdgcn_mfma_f32_16x16x32_bf16((a), (b), (c), 0, 0, 0)
#define LD8(p) (*(const bf16x8*)(p))

// ---------------- x fp32 -> bf16 ----------------
__global__ void k_cvt(const float* __restrict__ x, u16* __restrict__ xb, int n4) {
  int i = blockIdx.x * 256 + threadIdx.x;
  if (i < n4) {
    float4 v = ((const float4*)x)[i];
    bf16x4 o;
    o[0] = (__bf16)v.x; o[1] = (__bf16)v.y; o[2] = (__bf16)v.z; o[3] = (__bf16)v.w;
    ((bf16x4*)xb)[i] = o;
  }
}

// ---------------- W [K,N] fp32 -> Wt [N,K] bf16 (tile transpose) ----------------
__global__ void k_twt(const float* __restrict__ w0, const float* __restrict__ w1,
                      const float* __restrict__ w2, const float* __restrict__ w3,
                      u16* __restrict__ t0, u16* __restrict__ t1,
                      u16* __restrict__ t2, u16* __restrict__ t3) {
  __shared__ float t[32][33];
  int z = blockIdx.z;
  const float* w = z == 0 ? w0 : z == 1 ? w1 : z == 2 ? w2 : w3;
  u16* wt       = z == 0 ? t0 : z == 1 ? t1 : z == 2 ? t2 : t3;
  int n0 = blockIdx.x * 32, k0 = blockIdx.y * 32;
  int tx = threadIdx.x, ty = threadIdx.y;  // 32 x 8
  #pragma unroll
  for (int j = 0; j < 4; j++) t[ty + 8*j][tx] = w[(k0 + ty + 8*j) * D_ + n0 + tx];
  __syncthreads();
  #pragma unroll
  for (int j = 0; j < 4; j++) wt[(n0 + ty + 8*j) * D_ + k0 + tx] = f2bf(t[tx][ty + 8*j]);
}

// ---------------- GEMM body: C[m,n] = relu(A[m,:] . Bt[n,:] + bias[n]) * scale ----------------
__device__ __forceinline__
void gemm_body(const u16* __restrict__ A, const u16* __restrict__ Bt,
               const float* __restrict__ bias, void* __restrict__ out,
               float scale, int mode) {
  __shared__ __align__(16) u16 Al[128*64];
  __shared__ __align__(16) u16 Bl[128*64];
  int tid = threadIdx.x;
  int lane = tid & 63, w = tid >> 6;     // 8 waves: 2 (m) x 4 (n)
  int wr = w >> 2, wc = w & 3;
  int g = lane >> 4, qi = lane & 15;
  int m0 = blockIdx.y * 128, n0 = blockIdx.x * 128;
  int swzc = ((lane & 7) ^ (lane >> 3)) * 8;
  int lr8 = lane >> 3;

  f32x4 acc[4][2] = {};

  for (int k0 = 0; k0 < D_; k0 += 64) {
    #pragma unroll
    for (int j = 0; j < 2; j++) {
      int r0 = (w*2 + j) * 8;
      gl_lds16(A  + (m0 + r0 + lr8) * D_ + k0 + swzc, &Al[r0 * 64]);
      gl_lds16(Bt + (n0 + r0 + lr8) * D_ + k0 + swzc, &Bl[r0 * 64]);
    }
    __syncthreads();
    #pragma unroll
    for (int h = 0; h < 2; h++) {
      bf16x8 a[4], bq[2];
      #pragma unroll
      for (int i = 0; i < 4; i++) {
        int row = wr*64 + i*16 + qi;
        int c = (h*4 + g) ^ (row & 7);
        a[i] = LD8(&Al[row*64 + c*8]);
      }
      #pragma unroll
      for (int jn = 0; jn < 2; jn++) {
        int row = wc*32 + jn*16 + qi;
        int c = (h*4 + g) ^ (row & 7);
        bq[jn] = LD8(&Bl[row*64 + c*8]);
      }
      #pragma unroll
      for (int i = 0; i < 4; i++)
        #pragma unroll
        for (int jn = 0; jn < 2; jn++)
          acc[i][jn] = MM(a[i], bq[jn], acc[i][jn]);
    }
    __syncthreads();
  }

  #pragma unroll
  for (int i = 0; i < 4; i++)
    #pragma unroll
    for (int jn = 0; jn < 2; jn++) {
      int col = n0 + wc*32 + jn*16 + qi;
      float bs = bias[col];
      if (mode == 1) {
        int row0 = m0 + wr*64 + i*16 + g*4;
        int bb = row0 >> 12, ss0 = row0 & (S_ - 1);
        int hh = col >> 6, dd = col & 63;
        bf16x4 pk;
        pk[0] = (__bf16)(fmaxf(acc[i][jn][0] + bs, 0.0f) * scale);
        pk[1] = (__bf16)(fmaxf(acc[i][jn][1] + bs, 0.0f) * scale);
        pk[2] = (__bf16)(fmaxf(acc[i][jn][2] + bs, 0.0f) * scale);
        pk[3] = (__bf16)(fmaxf(acc[i][jn][3] + bs, 0.0f) * scale);
        *(bf16x4*)&((u16*)out)[((bb*H_ + hh)*DH_ + dd)*S_ + ss0] = pk;
      } else {
        #pragma unroll
        for (int ii = 0; ii < 4; ii++) {
          int row = m0 + wr*64 + i*16 + g*4 + ii;
          float v = fmaxf(acc[i][jn][ii] + bs, 0.0f) * scale;
          if (mode == 2) {
            ((float*)out)[row * D_ + col] = v;
          } else {
            int bb = row >> 12, ss = row & (S_ - 1);
            int hh = col >> 6, dd = col & 63;
            ((u16*)out)[((bb*H_ + hh)*S_ + ss)*DH_ + dd] = f2bf(v);
          }
        }
      }
    }
}

__global__ __launch_bounds__(512, 2)
void k_qkv(const u16* __restrict__ A,
           const u16* __restrict__ btq, const u16* __restrict__ btk, const u16* __restrict__ btv,
           const float* __restrict__ bq, const float* __restrict__ bk, const float* __restrict__ bv,
           u16* __restrict__ q, u16* __restrict__ k, u16* __restrict__ v) {
  int z = blockIdx.z;
  if (z == 0)      gemm_body(A, btq, bq, q, 0.125f * LOG2E, 0);  // Q pre-scaled: 1/sqrt(DH) * log2(e)
  else if (z == 1) gemm_body(A, btk, bk, k, 1.0f, 0);
  else             gemm_body(A, btv, bv, v, 1.0f, 1);
}

__global__ __launch_bounds__(512, 2)
void k_go(const u16* __restrict__ A, const u16* __restrict__ bt,
          const float* __restrict__ bias, float* __restrict__ out) {
  gemm_body(A, bt, bias, out, 1.0f, 2);
}

// ---------------- flash attention: 32 q-rows/wave, two q-sets sharing K/V frags ----------------
// Swapped QK^T, m == 0 (shift-invariant; base-2 logits bounded ~6), KV tile 64,
// dbuf + vmcnt(4), all LDS offsets hoisted, compile-time buf via template.
// Q: [B,H,S,64] bf16 (pre-scaled by log2e/8), K: [B,H,S,64], Vt: [B,H,64,S].
template<int BUF, int LAST>
__device__ __forceinline__ void attn_tile(
    const u16*& kp0, const u16*& kp1, const u16*& vp0, const u16*& vp1,
    u16* (&kdst)[2][2], u16* (&vdst)[2][2],
    const u16* Kl0, const u16* Kl1, const u16* Vl0, const u16* Vl1,
    char* Pw, const int (&fo)[4][2], const int (&pwo)[4], int pr0, int pr1,
    bf16x8 aqA0, bf16x8 aqA1, bf16x8 aqB0, bf16x8 aqB1,
    f32x4 (&oA)[4], f32x4 (&oB)[4], float& lA, float& lB) {
  if (!LAST) {
    gl_lds16(kp0, kdst[BUF^1][0]);
    gl_lds16(kp1, kdst[BUF^1][1]);
    gl_lds16(vp0, vdst[BUF^1][0]);
    gl_lds16(vp1, vdst[BUF^1][1]);
    kp0 += 64*DH_; kp1 += 64*DH_; vp0 += 64; vp1 += 64;
    asm volatile("s_waitcnt vmcnt(4)" ::: "memory");
  } else {
    asm volatile("s_waitcnt vmcnt(0)" ::: "memory");
  }
  __builtin_amdgcn_s_barrier();
  __builtin_amdgcn_sched_barrier(0);
  const char* Kb = (const char*)(BUF ? Kl1 : Kl0);
  const char* Vb = (const char*)(BUF ? Vl1 : Vl0);
  const f32x4 zro = {0.f, 0.f, 0.f, 0.f};

  f32x4 sA[4], sB[4];
  #pragma unroll
  for (int kt = 0; kt < 4; kt++) {
    bf16x8 k0 = LD8(Kb + fo[kt][0]);   // K frag read once,
    bf16x8 k1 = LD8(Kb + fo[kt][1]);   // feeds both q-sets
    sA[kt] = MM(k1, aqA1, MM(k0, aqA0, zro));
    sB[kt] = MM(k1, aqB1, MM(k0, aqB0, zro));
  }

  float suA = 0.0f, suB = 0.0f;
  #pragma unroll
  for (int kt = 0; kt < 4; kt++) {
    float a0 = EXP2(sA[kt][0]), a1 = EXP2(sA[kt][1]);
    float a2 = EXP2(sA[kt][2]), a3 = EXP2(sA[kt][3]);
    suA += (a0+a1)+(a2+a3);
    bf16x4 pa; pa[0]=(__bf16)a0; pa[1]=(__bf16)a1; pa[2]=(__bf16)a2; pa[3]=(__bf16)a3;
    *(bf16x4*)(Pw + pwo[kt]) = pa;
    float b0 = EXP2(sB[kt][0]), b1 = EXP2(sB[kt][1]);
    float b2 = EXP2(sB[kt][2]), b3 = EXP2(sB[kt][3]);
    suB += (b0+b1)+(b2+b3);
    bf16x4 pb; pb[0]=(__bf16)b0; pb[1]=(__bf16)b1; pb[2]=(__bf16)b2; pb[3]=(__bf16)b3;
    *(bf16x4*)(Pw + 2048 + pwo[kt]) = pb;
  }
  lA += suA; lB += suB;

  __builtin_amdgcn_s_setprio(1);
  #pragma unroll
  for (int kh = 0; kh < 2; kh++) {
    bf16x8 apA = LD8(Pw + (kh ? pr1 : pr0));
    bf16x8 apB = LD8(Pw + 2048 + (kh ? pr1 : pr0));
    #pragma unroll
    for (int nt = 0; nt < 4; nt++) {
      bf16x8 vf = LD8(Vb + fo[nt][kh]);   // V frag read once, feeds both sets
      oA[nt] = MM(apA, vf, oA[nt]);
      oB[nt] = MM(apB, vf, oB[nt]);
    }
  }
  __builtin_amdgcn_s_setprio(0);
  __builtin_amdgcn_sched_barrier(0);
  __builtin_amdgcn_s_barrier();
}

__global__ __launch_bounds__(256, 2)
void k_attn(const u16* __restrict__ Q, const u16* __restrict__ K,
            const u16* __restrict__ Vt, u16* __restrict__ O) {
  __shared__ __align__(16) u16 Kl[2][64*64];   // [buf][key][dh]      16 KB
  __shared__ __align__(16) u16 Vl[2][64*64];   // [buf][dh][key]      16 KB
  __shared__ __align__(16) u16 Pl[4][32*64];   // per-wave [q32][key] 16 KB
  const int tid = threadIdx.x;
  const int lane = tid & 63, w = tid >> 6;
  const int g = lane >> 4, qi = lane & 15, qi7 = qi & 7;

  // XCD head-affinity: 512 blocks, 64/XCD; each XCD owns 2 (b,h) pairs
  const int bid = blockIdx.x;
  const int xcd = bid & 7, idx = bid >> 3;     // idx 0..63
  const int hb = xcd * 2 + (idx & 1);          // 0..15
  const int qt = idx >> 1;                     // 0..31
  const int b = hb >> 3, h = hb & 7;

  const u16* Qh = Q  + ((b*H_ + h) * S_) * DH_;
  const u16* Kh = K  + ((b*H_ + h) * S_) * DH_;
  const u16* Vh = Vt + ((b*H_ + h) * DH_) * S_;
  const int q0 = qt*128 + w*32;                // 32 q-rows per wave

  const bf16x8 aqA0 = LD8(&Qh[(q0 + qi)*DH_ + g*8]);
  const bf16x8 aqA1 = LD8(&Qh[(q0 + qi)*DH_ + 32 + g*8]);
  const bf16x8 aqB0 = LD8(&Qh[(q0 + 16 + qi)*DH_ + g*8]);
  const bf16x8 aqB1 = LD8(&Qh[(q0 + 16 + qi)*DH_ + 32 + g*8]);

  f32x4 oA[4] = {}, oB[4] = {};
  float lA = 0.0f, lB = 0.0f;

  const int swzc = ((lane & 7) ^ (lane >> 3)) * 8;
  const int lr8 = lane >> 3;

  // hoisted LDS byte offsets (loop-invariant)
  int fo[4][2];        // K/V frag: row rt*16+qi, chunk (kh*4+g)^qi7
  #pragma unroll
  for (int rt = 0; rt < 4; rt++)
    #pragma unroll
    for (int kh = 0; kh < 2; kh++)
      fo[rt][kh] = (rt*16 + qi)*128 + (((kh*4 + g) ^ qi7)*16);
  int pwo[4];          // P write: row qi, chunk (kt*2+(g>>1))^qi7, half g&1
  #pragma unroll
  for (int kt = 0; kt < 4; kt++)
    pwo[kt] = qi*128 + (((kt*2 + (g >> 1)) ^ qi7)*16) + (g & 1)*8;
  const int pr0 = qi*128 + ((g ^ qi7)*16);
  const int pr1 = qi*128 + (((4 + g) ^ qi7)*16);
  char* Pw = (char*)Pl[w];

  // staging pointers (advance one KV tile per call)
  const u16* kp0 = Kh + (w*16 + lr8)*DH_ + swzc;
  const u16* kp1 = kp0 + 8*DH_;
  const u16* vp0 = Vh + (w*16 + lr8)*S_ + swzc;
  const u16* vp1 = vp0 + 8*S_;
  u16* kdst[2][2];
  u16* vdst[2][2];
  #pragma unroll
  for (int bb2 = 0; bb2 < 2; bb2++)
    #pragma unroll
    for (int j = 0; j < 2; j++) {
      kdst[bb2][j] = &Kl[bb2][(w*16 + j*8)*64];
      vdst[bb2][j] = &Vl[bb2][(w*16 + j*8)*64];
    }

  // prologue: stage tile 0 -> buf 0
  gl_lds16(kp0, kdst[0][0]);
  gl_lds16(kp1, kdst[0][1]);
  gl_lds16(vp0, vdst[0][0]);
  gl_lds16(vp1, vdst[0][1]);
  kp0 += 64*DH_; kp1 += 64*DH_; vp0 += 64; vp1 += 64;

#define T(BUF, LAST) attn_tile<BUF, LAST>(kp0, kp1, vp0, vp1, kdst, vdst, \
    &Kl[0][0], &Kl[1][0], &Vl[0][0], &Vl[1][0], Pw, fo, pwo, pr0, pr1, \
    aqA0, aqA1, aqB0, aqB1, oA, oB, lA, lB)

  for (int i = 0; i < 31; ++i) {
    T(0, 0);
    T(1, 0);
  }
  T(0, 0);
  T(1, 1);
#undef T

  // denominators: reduce partials across the 4 g-groups
  lA += __shfl_xor(lA, 16); lA += __shfl_xor(lA, 32);
  lB += __shfl_xor(lB, 16); lB += __shfl_xor(lB, 32);
  float rvA = 1.0f / lA, rvB = 1.0f / lB;
  float rrA[4], rrB[4];
  #pragma unroll
  for (int i = 0; i < 4; i++) {
    rrA[i] = __shfl(rvA, g*4 + i);
    rrB[i] = __shfl(rvB, g*4 + i);
  }
  #pragma unroll
  for (int ii = 0; ii < 4; ii++) {
    int rowA = q0 + g*4 + ii;
    u16* oaro = O + (b*S_ + rowA)*D_ + h*64 + qi;
    oaro[0]  = f2bf(oA[0][ii] * rrA[ii]);
    oaro[16] = f2bf(oA[1][ii] * rrA[ii]);
    oaro[32] = f2bf(oA[2][ii] * rrA[ii]);
    oaro[48] = f2bf(oA[3][ii] * rrA[ii]);
    u16* obro = oaro + 16*D_;
    obro[0]  = f2bf(oB[0][ii] * rrB[ii]);
    obro[16] = f2bf(oB[1][ii] * rrB[ii]);
    obro[32] = f2bf(oB[2][ii] * rrB[ii]);
    obro[48] = f2bf(oB[3][ii] * rrB[ii]);
  }
}

extern "C" void kernel_launch(void* const* d_in, const int* in_sizes, int n_in,
                              void* d_out, int out_size, void* d_ws, size_t ws_size,
                              hipStream_t stream) {
  (void)in_sizes; (void)n_in; (void)out_size; (void)ws_size;
  const float* x  = (const float*)d_in[0];
  const float* Wq = (const float*)d_in[1];
  const float* bq = (const float*)d_in[2];
  const float* Wk = (const float*)d_in[3];
  const float* bk = (const float*)d_in[4];
  const float* Wv = (const float*)d_in[5];
  const float* bv = (const float*)d_in[6];
  const float* Wo = (const float*)d_in[7];
  const float* bo = (const float*)d_in[8];

  char* ws = (char*)d_ws;
  u16* xb  = (u16*)ws;                              // 8 MB (reused as Ob after attn)
  u16* wtq = (u16*)(ws + 8388608);                  // 4 x 512 KB
  u16* wtk = wtq + 512*512;
  u16* wtv = wtk + 512*512;
  u16* wto = wtv + 512*512;
  u16* Qh  = (u16*)(ws + 8388608 + 4*524288);       // 3 x 8 MB
  u16* Kh  = Qh + M_*D_;
  u16* Vt  = Kh + M_*D_;
  u16* Ob  = xb;

  k_cvt<<<4096, 256, 0, stream>>>(x, xb, M_*D_/4);
  k_twt<<<dim3(16,16,4), dim3(32,8), 0, stream>>>(Wq, Wk, Wv, Wo, wtq, wtk, wtv, wto);
  k_qkv<<<dim3(4,64,3), 512, 0, stream>>>(xb, wtq, wtk, wtv, bq, bk, bv, Qh, Kh, Vt);
  k_attn<<<512, 256, 0, stream>>>(Qh, Kh, Vt, Ob);
  k_go<<<dim3(4,64), 512, 0, stream>>>(Ob, wto, bo, (float*)d_out);
}

// Round 9
// 199.401 us; speedup vs baseline: 1.6947x; 1.0213x over previous
//
#include <hip/hip_runtime.h>
#include <stdint.h>

#define B_ 2
#define S_ 4096
#define D_ 512
#define H_ 8
#define DH_ 64
#define M_ (B_*S_)   // 8192
#define LOG2E 1.4426950408889634f

typedef unsigned short u16;
typedef __bf16 bf16x8 __attribute__((ext_vector_type(8)));
typedef __bf16 bf16x4 __attribute__((ext_vector_type(4)));
typedef float f32x4 __attribute__((ext_vector_type(4)));

#if defined(__has_builtin)
#if __has_builtin(__builtin_amdgcn_exp2f)
#define EXP2(x) __builtin_amdgcn_exp2f(x)
#else
#define EXP2(x) exp2f(x)
#endif
#else
#define EXP2(x) exp2f(x)
#endif

// f32 -> bf16 via compiler-native cast (RNE; lowers to HW cvt on gfx950)
__device__ __forceinline__ u16 f2bf(float f) {
  __bf16 b = (__bf16)f;
  return __builtin_bit_cast(u16, b);
}

// global -> LDS direct copy, 16B per lane; LDS dest = wave-uniform base + lane*16.
// NOTE: imm offset MUST stay 0 — R5 showed offset:1024 corrupts LDS on gfx950.
__device__ __forceinline__ void gl_lds16(const void* g, void* l) {
  __builtin_amdgcn_global_load_lds(
      (__attribute__((address_space(1))) void*)(void*)g,
      (__attribute__((address_space(3))) void*)l, 16, 0, 0);
}

#define MM(a, b, c) __builtin_amdgcn_mfma_f32_16x16x32_bf16((a), (b), (c), 0, 0, 0)
#define LD8(p) (*(const bf16x8*)(p))

// ---------------- fused prep: x fp32->bf16 (bid<4096) + W transpose (bid>=4096) ----------------
__global__ void k_prep(const float* __restrict__ x, u16* __restrict__ xb,
                       const float* __restrict__ w0, const float* __restrict__ w1,
                       const float* __restrict__ w2, const float* __restrict__ w3,
                       u16* __restrict__ t0, u16* __restrict__ t1,
                       u16* __restrict__ t2, u16* __restrict__ t3) {
  __shared__ float t[32][33];
  int bid = blockIdx.x, tid = threadIdx.x;
  if (bid < 4096) {
    int i = bid * 256 + tid;   // n4 = M_*D_/4 = 1048576 = 4096*256 exactly
    float4 v = ((const float4*)x)[i];
    bf16x4 o;
    o[0] = (__bf16)v.x; o[1] = (__bf16)v.y; o[2] = (__bf16)v.z; o[3] = (__bf16)v.w;
    ((bf16x4*)xb)[i] = o;
  } else {
    int zb = bid - 4096;               // 0..1023
    int z = zb >> 8;                   // 0..3
    int rem = zb & 255;
    int bx = rem & 15, by = rem >> 4;  // 16 x 16 tiles
    const float* w = z == 0 ? w0 : z == 1 ? w1 : z == 2 ? w2 : w3;
    u16* wt       = z == 0 ? t0 : z == 1 ? t1 : z == 2 ? t2 : t3;
    int n0 = bx * 32, k0 = by * 32;
    int tx = tid & 31, ty = tid >> 5;  // 32 x 8
    #pragma unroll
    for (int j = 0; j < 4; j++) t[ty + 8*j][tx] = w[(k0 + ty + 8*j) * D_ + n0 + tx];
    __syncthreads();
    #pragma unroll
    for (int j = 0; j < 4; j++) wt[(n0 + ty + 8*j) * D_ + k0 + tx] = f2bf(t[tx][ty + 8*j]);
  }
}

// ---------------- pipelined GEMM step (dbuf, compile-time buf, counted vmcnt) ----------------
template<int BUF, int LAST>
__device__ __forceinline__ void gemm_step(
    const u16*& Ap0, const u16*& Ap1, const u16*& Bp0, const u16*& Bp1,
    u16* (&Adst)[2][2], u16* (&Bdst)[2][2],
    const u16* Al0, const u16* Al1, const u16* Bl0, const u16* Bl1,
    const int (&afo)[2][4], const int (&bfo)[2][2], f32x4 (&acc)[4][2]) {
  if (!LAST) {
    gl_lds16(Ap0, Adst[BUF^1][0]);
    gl_lds16(Ap1, Adst[BUF^1][1]);
    gl_lds16(Bp0, Bdst[BUF^1][0]);
    gl_lds16(Bp1, Bdst[BUF^1][1]);
    Ap0 += 64; Ap1 += 64; Bp0 += 64; Bp1 += 64;
    asm volatile("s_waitcnt vmcnt(4)" ::: "memory");  // step's own 4 loads landed
  } else {
    asm volatile("s_waitcnt vmcnt(0)" ::: "memory");
  }
  __builtin_amdgcn_s_barrier();
  __builtin_amdgcn_sched_barrier(0);
  const char* Ab = (const char*)(BUF ? Al1 : Al0);
  const char* Bb = (const char*)(BUF ? Bl1 : Bl0);
  #pragma unroll
  for (int h = 0; h < 2; h++) {
    bf16x8 a0 = LD8(Ab + afo[h][0]);
    bf16x8 a1 = LD8(Ab + afo[h][1]);
    bf16x8 a2 = LD8(Ab + afo[h][2]);
    bf16x8 a3 = LD8(Ab + afo[h][3]);
    bf16x8 b0 = LD8(Bb + bfo[h][0]);
    bf16x8 b1 = LD8(Bb + bfo[h][1]);
    acc[0][0] = MM(a0, b0, acc[0][0]); acc[0][1] = MM(a0, b1, acc[0][1]);
    acc[1][0] = MM(a1, b0, acc[1][0]); acc[1][1] = MM(a1, b1, acc[1][1]);
    acc[2][0] = MM(a2, b0, acc[2][0]); acc[2][1] = MM(a2, b1, acc[2][1]);
    acc[3][0] = MM(a3, b0, acc[3][0]); acc[3][1] = MM(a3, b1, acc[3][1]);
  }
  __builtin_amdgcn_sched_barrier(0);
  __builtin_amdgcn_s_barrier();   // protect BUF from next step's staging
}

// ---------------- GEMM body: C[m,n] = relu(A[m,:] . Bt[n,:] + bias[n]) * scale ----------------
// mode 0: bf16 out [B,H,S,DH]; mode 1: bf16 out [B,H,DH,S]; mode 2: f32 out [M_,D_].
__device__ __forceinline__
void gemm_body(const u16* __restrict__ A, const u16* __restrict__ Bt,
               const float* __restrict__ bias, void* __restrict__ out,
               float scale, int mode) {
  __shared__ __align__(16) u16 Al[2][128*64];
  __shared__ __align__(16) u16 Bl[2][128*64];
  int tid = threadIdx.x;
  int lane = tid & 63, w = tid >> 6;     // 8 waves: 2 (m) x 4 (n)
  int wr = w >> 2, wc = w & 3;
  int g = lane >> 4, qi = lane & 15, qi7 = qi & 7;
  int m0 = blockIdx.y * 128, n0 = blockIdx.x * 128;
  int swzc = ((lane & 7) ^ (lane >> 3)) * 8;
  int lr8 = lane >> 3;

  f32x4 acc[4][2] = {};

  // hoisted LDS frag byte offsets (rows are 8-aligned so row&7 == qi7)
  int afo[2][4], bfo[2][2];
  #pragma unroll
  for (int h = 0; h < 2; h++) {
    #pragma unroll
    for (int i = 0; i < 4; i++)
      afo[h][i] = (wr*64 + i*16 + qi)*128 + (((h*4 + g) ^ qi7)*16);
    #pragma unroll
    for (int jn = 0; jn < 2; jn++)
      bfo[h][jn] = (wc*32 + jn*16 + qi)*128 + (((h*4 + g) ^ qi7)*16);
  }

  // staging pointers (advance 64 elems per K-step)
  const u16* Ap0 = A  + (m0 + w*16 + lr8)*D_ + swzc;
  const u16* Ap1 = Ap0 + 8*D_;
  const u16* Bp0 = Bt + (n0 + w*16 + lr8)*D_ + swzc;
  const u16* Bp1 = Bp0 + 8*D_;
  u16* Adst[2][2];
  u16* Bdst[2][2];
  #pragma unroll
  for (int bb2 = 0; bb2 < 2; bb2++)
    #pragma unroll
    for (int j = 0; j < 2; j++) {
      Adst[bb2][j] = &Al[bb2][(w*16 + j*8)*64];
      Bdst[bb2][j] = &Bl[bb2][(w*16 + j*8)*64];
    }

  // prologue: stage K-step 0 -> buf 0
  gl_lds16(Ap0, Adst[0][0]);
  gl_lds16(Ap1, Adst[0][1]);
  gl_lds16(Bp0, Bdst[0][0]);
  gl_lds16(Bp1, Bdst[0][1]);
  Ap0 += 64; Ap1 += 64; Bp0 += 64; Bp1 += 64;

#define GS(BUF, LAST) gemm_step<BUF, LAST>(Ap0, Ap1, Bp0, Bp1, Adst, Bdst, \
    Al[0], Al[1], Bl[0], Bl[1], afo, bfo, acc)
  GS(0,0); GS(1,0); GS(0,0); GS(1,0); GS(0,0); GS(1,0); GS(0,0); GS(1,1);
#undef GS

  #pragma unroll
  for (int i = 0; i < 4; i++)
    #pragma unroll
    for (int jn = 0; jn < 2; jn++) {
      int col = n0 + wc*32 + jn*16 + qi;
      float bs = bias[col];
      if (mode == 1) {
        int row0 = m0 + wr*64 + i*16 + g*4;
        int bb = row0 >> 12, ss0 = row0 & (S_ - 1);
        int hh = col >> 6, dd = col & 63;
        bf16x4 pk;
        pk[0] = (__bf16)(fmaxf(acc[i][jn][0] + bs, 0.0f) * scale);
        pk[1] = (__bf16)(fmaxf(acc[i][jn][1] + bs, 0.0f) * scale);
        pk[2] = (__bf16)(fmaxf(acc[i][jn][2] + bs, 0.0f) * scale);
        pk[3] = (__bf16)(fmaxf(acc[i][jn][3] + bs, 0.0f) * scale);
        *(bf16x4*)&((u16*)out)[((bb*H_ + hh)*DH_ + dd)*S_ + ss0] = pk;
      } else {
        #pragma unroll
        for (int ii = 0; ii < 4; ii++) {
          int row = m0 + wr*64 + i*16 + g*4 + ii;
          float v = fmaxf(acc[i][jn][ii] + bs, 0.0f) * scale;
          if (mode == 2) {
            ((float*)out)[row * D_ + col] = v;
          } else {
            int bb = row >> 12, ss = row & (S_ - 1);
            int hh = col >> 6, dd = col & 63;
            ((u16*)out)[((bb*H_ + hh)*S_ + ss)*DH_ + dd] = f2bf(v);
          }
        }
      }
    }
}

__global__ __launch_bounds__(512, 2)
void k_qkv(const u16* __restrict__ A,
           const u16* __restrict__ btq, const u16* __restrict__ btk, const u16* __restrict__ btv,
           const float* __restrict__ bq, const float* __restrict__ bk, const float* __restrict__ bv,
           u16* __restrict__ q, u16* __restrict__ k, u16* __restrict__ v) {
  int z = blockIdx.z;
  if (z == 0)      gemm_body(A, btq, bq, q, 0.125f * LOG2E, 0);  // Q pre-scaled: 1/sqrt(DH) * log2(e)
  else if (z == 1) gemm_body(A, btk, bk, k, 1.0f, 0);
  else             gemm_body(A, btv, bv, v, 1.0f, 1);
}

__global__ __launch_bounds__(512, 2)
void k_go(const u16* __restrict__ A, const u16* __restrict__ bt,
          const float* __restrict__ bias, float* __restrict__ out) {
  gemm_body(A, bt, bias, out, 1.0f, 2);
}

// ---------------- flash attention: 32 q-rows/wave, two q-sets sharing K/V frags ----------------
// (byte-identical to R8's k_attn)
template<int BUF, int LAST>
__device__ __forceinline__ void attn_tile(
    const u16*& kp0, const u16*& kp1, const u16*& vp0, const u16*& vp1,
    u16* (&kdst)[2][2], u16* (&vdst)[2][2],
    const u16* Kl0, const u16* Kl1, const u16* Vl0, const u16* Vl1,
    char* Pw, const int (&fo)[4][2], const int (&pwo)[4], int pr0, int pr1,
    bf16x8 aqA0, bf16x8 aqA1, bf16x8 aqB0, bf16x8 aqB1,
    f32x4 (&oA)[4], f32x4 (&oB)[4], float& lA, float& lB) {
  if (!LAST) {
    gl_lds16(kp0, kdst[BUF^1][0]);
    gl_lds16(kp1, kdst[BUF^1][1]);
    gl_lds16(vp0, vdst[BUF^1][0]);
    gl_lds16(vp1, vdst[BUF^1][1]);
    kp0 += 64*DH_; kp1 += 64*DH_; vp0 += 64; vp1 += 64;
    asm volatile("s_waitcnt vmcnt(4)" ::: "memory");
  } else {
    asm volatile("s_waitcnt vmcnt(0)" ::: "memory");
  }
  __builtin_amdgcn_s_barrier();
  __builtin_amdgcn_sched_barrier(0);
  const char* Kb = (const char*)(BUF ? Kl1 : Kl0);
  const char* Vb = (const char*)(BUF ? Vl1 : Vl0);
  const f32x4 zro = {0.f, 0.f, 0.f, 0.f};

  f32x4 sA[4], sB[4];
  #pragma unroll
  for (int kt = 0; kt < 4; kt++) {
    bf16x8 k0 = LD8(Kb + fo[kt][0]);   // K frag read once,
    bf16x8 k1 = LD8(Kb + fo[kt][1]);   // feeds both q-sets
    sA[kt] = MM(k1, aqA1, MM(k0, aqA0, zro));
    sB[kt] = MM(k1, aqB1, MM(k0, aqB0, zro));
  }

  float suA = 0.0f, suB = 0.0f;
  #pragma unroll
  for (int kt = 0; kt < 4; kt++) {
    float a0 = EXP2(sA[kt][0]), a1 = EXP2(sA[kt][1]);
    float a2 = EXP2(sA[kt][2]), a3 = EXP2(sA[kt][3]);
    suA += (a0+a1)+(a2+a3);
    bf16x4 pa; pa[0]=(__bf16)a0; pa[1]=(__bf16)a1; pa[2]=(__bf16)a2; pa[3]=(__bf16)a3;
    *(bf16x4*)(Pw + pwo[kt]) = pa;
    float b0 = EXP2(sB[kt][0]), b1 = EXP2(sB[kt][1]);
    float b2 = EXP2(sB[kt][2]), b3 = EXP2(sB[kt][3]);
    suB += (b0+b1)+(b2+b3);
    bf16x4 pb; pb[0]=(__bf16)b0; pb[1]=(__bf16)b1; pb[2]=(__bf16)b2; pb[3]=(__bf16)b3;
    *(bf16x4*)(Pw + 2048 + pwo[kt]) = pb;
  }
  lA += suA; lB += suB;

  __builtin_amdgcn_s_setprio(1);
  #pragma unroll
  for (int kh = 0; kh < 2; kh++) {
    bf16x8 apA = LD8(Pw + (kh ? pr1 : pr0));
    bf16x8 apB = LD8(Pw + 2048 + (kh ? pr1 : pr0));
    #pragma unroll
    for (int nt = 0; nt < 4; nt++) {
      bf16x8 vf = LD8(Vb + fo[nt][kh]);   // V frag read once, feeds both sets
      oA[nt] = MM(apA, vf, oA[nt]);
      oB[nt] = MM(apB, vf, oB[nt]);
    }
  }
  __builtin_amdgcn_s_setprio(0);
  __builtin_amdgcn_sched_barrier(0);
  __builtin_amdgcn_s_barrier();
}

__global__ __launch_bounds__(256, 2)
void k_attn(const u16* __restrict__ Q, const u16* __restrict__ K,
            const u16* __restrict__ Vt, u16* __restrict__ O) {
  __shared__ __align__(16) u16 Kl[2][64*64];   // [buf][key][dh]      16 KB
  __shared__ __align__(16) u16 Vl[2][64*64];   // [buf][dh][key]      16 KB
  __shared__ __align__(16) u16 Pl[4][32*64];   // per-wave [q32][key] 16 KB
  const int tid = threadIdx.x;
  const int lane = tid & 63, w = tid >> 6;
  const int g = lane >> 4, qi = lane & 15, qi7 = qi & 7;

  // XCD head-affinity: 512 blocks, 64/XCD; each XCD owns 2 (b,h) pairs
  const int bid = blockIdx.x;
  const int xcd = bid & 7, idx = bid >> 3;     // idx 0..63
  const int hb = xcd * 2 + (idx & 1);          // 0..15
  const int qt = idx >> 1;                     // 0..31
  const int b = hb >> 3, h = hb & 7;

  const u16* Qh = Q  + ((b*H_ + h) * S_) * DH_;
  const u16* Kh = K  + ((b*H_ + h) * S_) * DH_;
  const u16* Vh = Vt + ((b*H_ + h) * DH_) * S_;
  const int q0 = qt*128 + w*32;                // 32 q-rows per wave

  const bf16x8 aqA0 = LD8(&Qh[(q0 + qi)*DH_ + g*8]);
  const bf16x8 aqA1 = LD8(&Qh[(q0 + qi)*DH_ + 32 + g*8]);
  const bf16x8 aqB0 = LD8(&Qh[(q0 + 16 + qi)*DH_ + g*8]);
  const bf16x8 aqB1 = LD8(&Qh[(q0 + 16 + qi)*DH_ + 32 + g*8]);

  f32x4 oA[4] = {}, oB[4] = {};
  float lA = 0.0f, lB = 0.0f;

  const int swzc = ((lane & 7) ^ (lane >> 3)) * 8;
  const int lr8 = lane >> 3;

  // hoisted LDS byte offsets (loop-invariant)
  int fo[4][2];        // K/V frag: row rt*16+qi, chunk (kh*4+g)^qi7
  #pragma unroll
  for (int rt = 0; rt < 4; rt++)
    #pragma unroll
    for (int kh = 0; kh < 2; kh++)
      fo[rt][kh] = (rt*16 + qi)*128 + (((kh*4 + g) ^ qi7)*16);
  int pwo[4];          // P write: row qi, chunk (kt*2+(g>>1))^qi7, half g&1
  #pragma unroll
  for (int kt = 0; kt < 4; kt++)
    pwo[kt] = qi*128 + (((kt*2 + (g >> 1)) ^ qi7)*16) + (g & 1)*8;
  const int pr0 = qi*128 + ((g ^ qi7)*16);
  const int pr1 = qi*128 + (((4 + g) ^ qi7)*16);
  char* Pw = (char*)Pl[w];

  // staging pointers (advance one KV tile per call)
  const u16* kp0 = Kh + (w*16 + lr8)*DH_ + swzc;
  const u16* kp1 = kp0 + 8*DH_;
  const u16* vp0 = Vh + (w*16 + lr8)*S_ + swzc;
  const u16* vp1 = vp0 + 8*S_;
  u16* kdst[2][2];
  u16* vdst[2][2];
  #pragma unroll
  for (int bb2 = 0; bb2 < 2; bb2++)
    #pragma unroll
    for (int j = 0; j < 2; j++) {
      kdst[bb2][j] = &Kl[bb2][(w*16 + j*8)*64];
      vdst[bb2][j] = &Vl[bb2][(w*16 + j*8)*64];
    }

  // prologue: stage tile 0 -> buf 0
  gl_lds16(kp0, kdst[0][0]);
  gl_lds16(kp1, kdst[0][1]);
  gl_lds16(vp0, vdst[0][0]);
  gl_lds16(vp1, vdst[0][1]);
  kp0 += 64*DH_; kp1 += 64*DH_; vp0 += 64; vp1 += 64;

#define T(BUF, LAST) attn_tile<BUF, LAST>(kp0, kp1, vp0, vp1, kdst, vdst, \
    &Kl[0][0], &Kl[1][0], &Vl[0][0], &Vl[1][0], Pw, fo, pwo, pr0, pr1, \
    aqA0, aqA1, aqB0, aqB1, oA, oB, lA, lB)

  for (int i = 0; i < 31; ++i) {
    T(0, 0);
    T(1, 0);
  }
  T(0, 0);
  T(1, 1);
#undef T

  // denominators: reduce partials across the 4 g-groups
  lA += __shfl_xor(lA, 16); lA += __shfl_xor(lA, 32);
  lB += __shfl_xor(lB, 16); lB += __shfl_xor(lB, 32);
  float rvA = 1.0f / lA, rvB = 1.0f / lB;
  float rrA[4], rrB[4];
  #pragma unroll
  for (int i = 0; i < 4; i++) {
    rrA[i] = __shfl(rvA, g*4 + i);
    rrB[i] = __shfl(rvB, g*4 + i);
  }
  #pragma unroll
  for (int ii = 0; ii < 4; ii++) {
    int rowA = q0 + g*4 + ii;
    u16* oaro = O + (b*S_ + rowA)*D_ + h*64 + qi;
    oaro[0]  = f2bf(oA[0][ii] * rrA[ii]);
    oaro[16] = f2bf(oA[1][ii] * rrA[ii]);
    oaro[32] = f2bf(oA[2][ii] * rrA[ii]);
    oaro[48] = f2bf(oA[3][ii] * rrA[ii]);
    u16* obro = oaro + 16*D_;
    obro[0]  = f2bf(oB[0][ii] * rrB[ii]);
    obro[16] = f2bf(oB[1][ii] * rrB[ii]);
    obro[32] = f2bf(oB[2][ii] * rrB[ii]);
    obro[48] = f2bf(oB[3][ii] * rrB[ii]);
  }
}

extern "C" void kernel_launch(void* const* d_in, const int* in_sizes, int n_in,
                              void* d_out, int out_size, void* d_ws, size_t ws_size,
                              hipStream_t stream) {
  (void)in_sizes; (void)n_in; (void)out_size; (void)ws_size;
  const float* x  = (const float*)d_in[0];
  const float* Wq = (const float*)d_in[1];
  const float* bq = (const float*)d_in[2];
  const float* Wk = (const float*)d_in[3];
  const float* bk = (const float*)d_in[4];
  const float* Wv = (const float*)d_in[5];
  const float* bv = (const float*)d_in[6];
  const float* Wo = (const float*)d_in[7];
  const float* bo = (const float*)d_in[8];

  char* ws = (char*)d_ws;
  u16* xb  = (u16*)ws;                              // 8 MB (reused as Ob after attn)
  u16* wtq = (u16*)(ws + 8388608);                  // 4 x 512 KB
  u16* wtk = wtq + 512*512;
  u16* wtv = wtk + 512*512;
  u16* wto = wtv + 512*512;
  u16* Qh  = (u16*)(ws + 8388608 + 4*524288);       // 3 x 8 MB
  u16* Kh  = Qh + M_*D_;
  u16* Vt  = Kh + M_*D_;
  u16* Ob  = xb;

  k_prep<<<5120, 256, 0, stream>>>(x, xb, Wq, Wk, Wv, Wo, wtq, wtk, wtv, wto);
  k_qkv<<<dim3(4,64,3), 512, 0, stream>>>(xb, wtq, wtk, wtv, bq, bk, bv, Qh, Kh, Vt);
  k_attn<<<512, 256, 0, stream>>>(Qh, Kh, Vt, Ob);
  k_go<<<dim3(4,64), 512, 0, stream>>>(Ob, wto, bo, (float*)d_out);
}